// Round 1
// baseline (5851.569 us; speedup 1.0000x reference)
//
#include <hip/hip_runtime.h>
#include <hip/hip_bf16.h>
#include <math.h>

#define NEG_ATT 0.2f
#define NEG_ACT 0.01f

// ---------------------------------------------------------------- utilities
__device__ __forceinline__ void atomicMaxF(float* addr, float v) {
    // order-preserving int trick; works for mixed signs, init must be -inf
    if (v >= 0.f) atomicMax((int*)addr, __float_as_int(v));
    else          atomicMin((unsigned int*)addr, __float_as_uint(v));
}

// ---------------------------------------------------------------- init
// g1[n][k] = b1[k]; z[n][k] = b2[k]; m = -inf; s = 0
__global__ void k_init(float* __restrict__ g1, const float* __restrict__ b1,
                       float* __restrict__ zout, const float* __restrict__ b2,
                       float* __restrict__ m1, float* __restrict__ s1,
                       float* __restrict__ m2, float* __restrict__ s2, int N) {
    int i = blockIdx.x * blockDim.x + threadIdx.x;
    if (i < N * 128) g1[i] = b1[i & 127];
    if (i < N * 64)  zout[i] = b2[i & 63];
    if (i < N * 4) { m1[i] = -INFINITY; s1[i] = 0.f; }
    if (i < N)     { m2[i] = -INFINITY; s2[i] = 0.f; }
}

// ---------------------------------------------------------------- GEMM1: h1 = x @ W1   [N,128]x[128,128]
__global__ void k_gemm1(const float* __restrict__ x, const float* __restrict__ W1,
                        float* __restrict__ h1, int N) {
    __shared__ float xs[8][128];
    const int j = threadIdx.x;              // output col 0..127
    const int row0 = blockIdx.x * 8;
    #pragma unroll
    for (int r = 0; r < 8; ++r) {
        int n = row0 + r;
        xs[r][j] = (n < N) ? x[(long)n * 128 + j] : 0.f;
    }
    __syncthreads();
    float acc[8];
    #pragma unroll
    for (int r = 0; r < 8; ++r) acc[r] = 0.f;
    for (int k = 0; k < 128; ++k) {
        float w = W1[k * 128 + j];
        #pragma unroll
        for (int r = 0; r < 8; ++r) acc[r] = fmaf(xs[r][k], w, acc[r]);
    }
    #pragma unroll
    for (int r = 0; r < 8; ++r) {
        int n = row0 + r;
        if (n < N) h1[(long)n * 128 + j] = acc[r];
    }
}

// ---------------------------------------------------------------- attention coefficients layer 1
// a1s[n][h] = sum_c h1[n][h*32+c]*att_src[h][c]  (flattened layouts match)
__global__ void k_att1(const float* __restrict__ h1, const float* __restrict__ as,
                       const float* __restrict__ ad,
                       float* __restrict__ a1s, float* __restrict__ a1d, int N) {
    const int n = blockIdx.x, j = threadIdx.x;   // 128 threads
    float h = h1[(long)n * 128 + j];
    float vs = h * as[j], vd = h * ad[j];
    #pragma unroll
    for (int m = 16; m >= 1; m >>= 1) {
        vs += __shfl_xor(vs, m, 32);
        vd += __shfl_xor(vd, m, 32);
    }
    if ((j & 31) == 0) { a1s[n * 4 + (j >> 5)] = vs; a1d[n * 4 + (j >> 5)] = vd; }
}

// ---------------------------------------------------------------- edge softmax max (layer 1, 4 heads)
__global__ void k_emax1(const int* __restrict__ ei, int E, int N,
                        const float* __restrict__ a1s, const float* __restrict__ a1d,
                        float* __restrict__ m1) {
    int e = blockIdx.x * blockDim.x + threadIdx.x;
    int E2 = E + N;
    if (e >= E2) return;
    int s, d;
    if (e < E) { s = ei[e]; d = ei[E + e]; } else { s = d = e - E; }
    #pragma unroll
    for (int h = 0; h < 4; ++h) {
        float att = a1s[s * 4 + h] + a1d[d * 4 + h];
        att = att > 0.f ? att : NEG_ATT * att;
        atomicMaxF(&m1[d * 4 + h], att);
    }
}

// ---------------------------------------------------------------- edge exp + denom (layer 1)
__global__ void k_eexp1(const int* __restrict__ ei, int E, int N,
                        const float* __restrict__ a1s, const float* __restrict__ a1d,
                        const float* __restrict__ m1, float* __restrict__ e1,
                        float* __restrict__ s1) {
    int e = blockIdx.x * blockDim.x + threadIdx.x;
    int E2 = E + N;
    if (e >= E2) return;
    int s, d;
    if (e < E) { s = ei[e]; d = ei[E + e]; } else { s = d = e - E; }
    const float4 vs = *(const float4*)&a1s[s * 4];
    const float4 vd = *(const float4*)&a1d[d * 4];
    const float4 vm = *(const float4*)&m1[d * 4];
    float att0 = vs.x + vd.x, att1 = vs.y + vd.y, att2 = vs.z + vd.z, att3 = vs.w + vd.w;
    att0 = att0 > 0.f ? att0 : NEG_ATT * att0;
    att1 = att1 > 0.f ? att1 : NEG_ATT * att1;
    att2 = att2 > 0.f ? att2 : NEG_ATT * att2;
    att3 = att3 > 0.f ? att3 : NEG_ATT * att3;
    float4 w;
    w.x = expf(att0 - vm.x); w.y = expf(att1 - vm.y);
    w.z = expf(att2 - vm.z); w.w = expf(att3 - vm.w);
    *(float4*)&e1[(long)e * 4] = w;
    atomicAdd(&s1[d * 4 + 0], w.x);
    atomicAdd(&s1[d * 4 + 1], w.y);
    atomicAdd(&s1[d * 4 + 2], w.z);
    atomicAdd(&s1[d * 4 + 3], w.w);
}

// ---------------------------------------------------------------- edge aggregate (layer 1): 32 lanes/edge, float4 each
__global__ void k_eaggr1(const int* __restrict__ ei, int E, int N,
                         const float* __restrict__ h1, const float* __restrict__ e1,
                         const float* __restrict__ s1, float* __restrict__ g1) {
    long tid = (long)blockIdx.x * blockDim.x + threadIdx.x;
    int lane = (int)(tid & 31);
    long e = tid >> 5;
    int E2 = E + N;
    if (e >= E2) return;
    int s, d;
    if (e < E) { s = ei[e]; d = ei[E + e]; } else { s = d = (int)e - E; }
    int h = lane >> 3;                       // 8 lanes (32 channels) per head
    float alpha = e1[e * 4 + h] / (s1[d * 4 + h] + 1e-16f);
    const float4 hv = *(const float4*)&h1[(long)s * 128 + lane * 4];
    float* out = &g1[(long)d * 128 + lane * 4];
    atomicAdd(out + 0, hv.x * alpha);
    atomicAdd(out + 1, hv.y * alpha);
    atomicAdd(out + 2, hv.z * alpha);
    atomicAdd(out + 3, hv.w * alpha);
}

// ---------------------------------------------------------------- GEMM2 fused: h2 = leaky(g1) @ W2, + a2s/a2d
__global__ void k_gemm2(const float* __restrict__ g1, const float* __restrict__ W2,
                        const float* __restrict__ a2srcv, const float* __restrict__ a2dstv,
                        float* __restrict__ h2, float* __restrict__ a2s, float* __restrict__ a2d,
                        int N) {
    __shared__ float xs[128];
    const int n = blockIdx.x, j = threadIdx.x;   // 64 threads
    for (int t = j; t < 128; t += 64) {
        float v = g1[(long)n * 128 + t];
        xs[t] = v > 0.f ? v : NEG_ACT * v;
    }
    __syncthreads();
    float acc = 0.f;
    for (int k = 0; k < 128; ++k) acc = fmaf(xs[k], W2[k * 64 + j], acc);
    h2[(long)n * 64 + j] = acc;
    float vs = acc * a2srcv[j], vd = acc * a2dstv[j];
    #pragma unroll
    for (int m = 32; m >= 1; m >>= 1) {
        vs += __shfl_xor(vs, m);
        vd += __shfl_xor(vd, m);
    }
    if (j == 0) { a2s[n] = vs; a2d[n] = vd; }
}

// ---------------------------------------------------------------- edge softmax (layer 2, 1 head)
__global__ void k_emax2(const int* __restrict__ ei, int E, int N,
                        const float* __restrict__ a2s, const float* __restrict__ a2d,
                        float* __restrict__ m2) {
    int e = blockIdx.x * blockDim.x + threadIdx.x;
    int E2 = E + N;
    if (e >= E2) return;
    int s, d;
    if (e < E) { s = ei[e]; d = ei[E + e]; } else { s = d = e - E; }
    float att = a2s[s] + a2d[d];
    att = att > 0.f ? att : NEG_ATT * att;
    atomicMaxF(&m2[d], att);
}

__global__ void k_eexp2(const int* __restrict__ ei, int E, int N,
                        const float* __restrict__ a2s, const float* __restrict__ a2d,
                        const float* __restrict__ m2, float* __restrict__ e2,
                        float* __restrict__ s2) {
    int e = blockIdx.x * blockDim.x + threadIdx.x;
    int E2 = E + N;
    if (e >= E2) return;
    int s, d;
    if (e < E) { s = ei[e]; d = ei[E + e]; } else { s = d = e - E; }
    float att = a2s[s] + a2d[d];
    att = att > 0.f ? att : NEG_ATT * att;
    float w = expf(att - m2[d]);
    e2[e] = w;
    atomicAdd(&s2[d], w);
}

// ---------------------------------------------------------------- edge aggregate (layer 2): 16 lanes/edge, float4
__global__ void k_eaggr2(const int* __restrict__ ei, int E, int N,
                         const float* __restrict__ h2, const float* __restrict__ e2,
                         const float* __restrict__ s2, float* __restrict__ zout) {
    long tid = (long)blockIdx.x * blockDim.x + threadIdx.x;
    int lane = (int)(tid & 15);
    long e = tid >> 4;
    int E2 = E + N;
    if (e >= E2) return;
    int s, d;
    if (e < E) { s = ei[e]; d = ei[E + e]; } else { s = d = (int)e - E; }
    float alpha = e2[e] / (s2[d] + 1e-16f);
    const float4 hv = *(const float4*)&h2[(long)s * 64 + lane * 4];
    float* out = &zout[(long)d * 64 + lane * 4];
    atomicAdd(out + 0, hv.x * alpha);
    atomicAdd(out + 1, hv.y * alpha);
    atomicAdd(out + 2, hv.z * alpha);
    atomicAdd(out + 3, hv.w * alpha);
}

// ---------------------------------------------------------------- decoder: per original edge, [128]->[32]->1 MLP
__global__ void k_dec(const int* __restrict__ ei, int E, const float* __restrict__ z,
                      const float* __restrict__ Wd1, const float* __restrict__ bd1,
                      const float* __restrict__ Wd2, const float* __restrict__ bd2,
                      float* __restrict__ pred) {
    __shared__ float fs[8][128];
    const int g = threadIdx.x >> 5, j = threadIdx.x & 31;
    long e = (long)blockIdx.x * 8 + g;
    bool valid = (e < E);
    if (valid) {
        int s = ei[e], d = ei[E + e];
        fs[g][j]      = z[(long)s * 64 + j];
        fs[g][32 + j] = z[(long)s * 64 + 32 + j];
        fs[g][64 + j] = z[(long)d * 64 + j];
        fs[g][96 + j] = z[(long)d * 64 + 32 + j];
    }
    __syncthreads();
    if (!valid) return;
    float acc = bd1[j];
    for (int k = 0; k < 128; ++k) acc = fmaf(fs[g][k], Wd1[k * 32 + j], acc);
    acc = acc > 0.f ? acc : 0.f;             // relu
    float p = acc * Wd2[j];
    #pragma unroll
    for (int m = 16; m >= 1; m >>= 1) p += __shfl_xor(p, m, 32);
    if (j == 0) pred[e] = p + bd2[0];
}

// ---------------------------------------------------------------- launch
extern "C" void kernel_launch(void* const* d_in, const int* in_sizes, int n_in,
                              void* d_out, int out_size, void* d_ws, size_t ws_size,
                              hipStream_t stream) {
    const float* x    = (const float*)d_in[0];
    const int*   ei   = (const int*)d_in[1];
    const float* W1   = (const float*)d_in[2];
    const float* a1sw = (const float*)d_in[3];
    const float* a1dw = (const float*)d_in[4];
    const float* b1   = (const float*)d_in[5];
    const float* W2   = (const float*)d_in[6];
    const float* a2sw = (const float*)d_in[7];
    const float* a2dw = (const float*)d_in[8];
    const float* b2   = (const float*)d_in[9];
    const float* Wd1  = (const float*)d_in[10];
    const float* bd1  = (const float*)d_in[11];
    const float* Wd2  = (const float*)d_in[12];
    const float* bd2  = (const float*)d_in[13];

    const int N = in_sizes[0] / 128;        // 50000
    const int E = in_sizes[1] / 2;          // 1600000
    const int E2 = E + N;

    float* pred = (float*)d_out;            // [E]
    float* zout = (float*)d_out + E;        // [N,64]

    // workspace layout
    float* W = (float*)d_ws;
    size_t o = 0;
    float* h1  = W + o; o += (size_t)N * 128;
    float* g1  = W + o; o += (size_t)N * 128;
    float* h2  = W + o; o += (size_t)N * 64;
    float* a1s = W + o; o += (size_t)N * 4;
    float* a1d = W + o; o += (size_t)N * 4;
    float* m1  = W + o; o += (size_t)N * 4;
    float* s1  = W + o; o += (size_t)N * 4;
    float* a2s = W + o; o += (size_t)N;
    float* a2d = W + o; o += (size_t)N;
    float* m2  = W + o; o += (size_t)N;
    float* s2  = W + o; o += (size_t)N;
    float* e1  = W + o; o += (size_t)E2 * 4;
    float* e2  = W + o; o += (size_t)E2;
    if (ws_size < o * sizeof(float)) return;   // insufficient scratch — fail loudly

    const int TB = 256;
    const int gE = (E2 + TB - 1) / TB;

    k_init<<<(N * 128 + TB - 1) / TB, TB, 0, stream>>>(g1, b1, zout, b2, m1, s1, m2, s2, N);
    k_gemm1<<<(N + 7) / 8, 128, 0, stream>>>(x, W1, h1, N);
    k_att1<<<N, 128, 0, stream>>>(h1, a1sw, a1dw, a1s, a1d, N);
    k_emax1<<<gE, TB, 0, stream>>>(ei, E, N, a1s, a1d, m1);
    k_eexp1<<<gE, TB, 0, stream>>>(ei, E, N, a1s, a1d, m1, e1, s1);
    {
        long threads = (long)E2 * 32;
        k_eaggr1<<<(int)((threads + TB - 1) / TB), TB, 0, stream>>>(ei, E, N, h1, e1, s1, g1);
    }
    k_gemm2<<<N, 64, 0, stream>>>(g1, W2, a2sw, a2dw, h2, a2s, a2d, N);
    k_emax2<<<gE, TB, 0, stream>>>(ei, E, N, a2s, a2d, m2);
    k_eexp2<<<gE, TB, 0, stream>>>(ei, E, N, a2s, a2d, m2, e2, s2);
    {
        long threads = (long)E2 * 16;
        k_eaggr2<<<(int)((threads + TB - 1) / TB), TB, 0, stream>>>(ei, E, N, h2, e2, s2, zout);
    }
    k_dec<<<(E + 7) / 8, 256, 0, stream>>>(ei, E, zout, Wd1, bd1, Wd2, bd2, pred);
}

// Round 2
// 1509.754 us; speedup vs baseline: 3.8758x; 3.8758x over previous
//
#include <hip/hip_runtime.h>
#include <hip/hip_bf16.h>
#include <math.h>

#define NEG_ATT 0.2f
#define NEG_ACT 0.01f
#define NEG_BIG -1e30f

// ============================ CSR build ============================
__global__ void k_zero(int* __restrict__ counts, int N) {
    int i = blockIdx.x * blockDim.x + threadIdx.x;
    if (i < N) counts[i] = 0;
}

__global__ void k_count(const int* __restrict__ ei, int E, int N, int* __restrict__ counts) {
    int e = blockIdx.x * blockDim.x + threadIdx.x;
    if (e >= E + N) return;
    int d = (e < E) ? ei[E + e] : e - E;
    atomicAdd(&counts[d], 1);
}

// single-block 1024-thread exclusive scan over counts[0..N) -> rowptr[0..N], cursor copy
__global__ void k_scan(const int* __restrict__ counts, int N,
                       int* __restrict__ rowptr, int* __restrict__ cursor) {
    __shared__ int ps[1024];
    const int t = threadIdx.x;
    const int C = (N + 1023) >> 10;
    const int lo = t * C, hi = min(lo + C, N);
    int sum = 0;
    for (int i = lo; i < hi; ++i) sum += counts[i];
    ps[t] = sum;
    __syncthreads();
    for (int off = 1; off < 1024; off <<= 1) {
        int v = (t >= off) ? ps[t - off] : 0;
        __syncthreads();
        ps[t] += v;
        __syncthreads();
    }
    int run = ps[t] - sum;   // exclusive prefix
    for (int i = lo; i < hi; ++i) {
        rowptr[i] = run; cursor[i] = run;
        run += counts[i];
    }
    if (t == 1023) rowptr[N] = ps[1023];
}

__global__ void k_scatter(const int* __restrict__ ei, int E, int N,
                          int* __restrict__ cursor, int* __restrict__ col) {
    int e = blockIdx.x * blockDim.x + threadIdx.x;
    if (e >= E + N) return;
    int s, d;
    if (e < E) { s = ei[e]; d = ei[E + e]; } else { s = d = e - E; }
    int pos = atomicAdd(&cursor[d], 1);
    col[pos] = s;
}

// ============================ GEMM1: h1 = x @ W1  [N,128]x[128,128] ============================
__global__ void k_gemm1(const float* __restrict__ x, const float* __restrict__ W1,
                        float* __restrict__ h1, int N) {
    __shared__ float xs[8][128];
    const int j = threadIdx.x;
    const int row0 = blockIdx.x * 8;
    #pragma unroll
    for (int r = 0; r < 8; ++r) {
        int n = row0 + r;
        xs[r][j] = (n < N) ? x[(long)n * 128 + j] : 0.f;
    }
    __syncthreads();
    float acc[8];
    #pragma unroll
    for (int r = 0; r < 8; ++r) acc[r] = 0.f;
    for (int k = 0; k < 128; ++k) {
        float w = W1[k * 128 + j];
        #pragma unroll
        for (int r = 0; r < 8; ++r) acc[r] = fmaf(xs[r][k], w, acc[r]);
    }
    #pragma unroll
    for (int r = 0; r < 8; ++r) {
        int n = row0 + r;
        if (n < N) h1[(long)n * 128 + j] = acc[r];
    }
}

// ============================ attention coeffs layer 1 ============================
__global__ void k_att1(const float* __restrict__ h1, const float* __restrict__ as,
                       const float* __restrict__ ad,
                       float* __restrict__ a1s, float* __restrict__ a1d, int N) {
    const int n = blockIdx.x, j = threadIdx.x;   // 128 threads
    float h = h1[(long)n * 128 + j];
    float vs = h * as[j], vd = h * ad[j];
    #pragma unroll
    for (int m = 16; m >= 1; m >>= 1) {
        vs += __shfl_xor(vs, m, 32);
        vd += __shfl_xor(vd, m, 32);
    }
    if ((j & 31) == 0) { a1s[n * 4 + (j >> 5)] = vs; a1d[n * 4 + (j >> 5)] = vd; }
}

// ============================ layer-1 fused softmax+aggregate, one wave per dst ============================
__global__ void k_aggr1(const int* __restrict__ rowptr, const int* __restrict__ col,
                        const float* __restrict__ h1, const float* __restrict__ a1s,
                        const float* __restrict__ a1d, const float* __restrict__ b1,
                        float* __restrict__ g1, int N) {
    const int wid = (blockIdx.x * blockDim.x + threadIdx.x) >> 6;
    const int lane = threadIdx.x & 63;
    if (wid >= N) return;
    const int d = wid;
    const int lo = rowptr[d], hi = rowptr[d + 1];
    const float4 ad4 = *(const float4*)&a1d[d * 4];

    // ---- phase 1: online softmax stats per head (strided over edges) ----
    float mx0 = NEG_BIG, mx1 = NEG_BIG, mx2 = NEG_BIG, mx3 = NEG_BIG;
    float sm0 = 0.f, sm1 = 0.f, sm2 = 0.f, sm3 = 0.f;
    for (int j = lo + lane; j < hi; j += 64) {
        int s = col[j];
        float4 as4 = *(const float4*)&a1s[s * 4];
        float a0 = as4.x + ad4.x, a1 = as4.y + ad4.y, a2 = as4.z + ad4.z, a3 = as4.w + ad4.w;
        a0 = a0 > 0.f ? a0 : NEG_ATT * a0;
        a1 = a1 > 0.f ? a1 : NEG_ATT * a1;
        a2 = a2 > 0.f ? a2 : NEG_ATT * a2;
        a3 = a3 > 0.f ? a3 : NEG_ATT * a3;
        float m;
        m = fmaxf(mx0, a0); sm0 = sm0 * __expf(mx0 - m) + __expf(a0 - m); mx0 = m;
        m = fmaxf(mx1, a1); sm1 = sm1 * __expf(mx1 - m) + __expf(a1 - m); mx1 = m;
        m = fmaxf(mx2, a2); sm2 = sm2 * __expf(mx2 - m) + __expf(a2 - m); mx2 = m;
        m = fmaxf(mx3, a3); sm3 = sm3 * __expf(mx3 - m) + __expf(a3 - m); mx3 = m;
    }
    // ---- wave-reduce (mx, sm) pairs ----
    #pragma unroll
    for (int off = 32; off >= 1; off >>= 1) {
        float mo, so, m;
        mo = __shfl_xor(mx0, off); so = __shfl_xor(sm0, off);
        m = fmaxf(mx0, mo); sm0 = sm0 * __expf(mx0 - m) + so * __expf(mo - m); mx0 = m;
        mo = __shfl_xor(mx1, off); so = __shfl_xor(sm1, off);
        m = fmaxf(mx1, mo); sm1 = sm1 * __expf(mx1 - m) + so * __expf(mo - m); mx1 = m;
        mo = __shfl_xor(mx2, off); so = __shfl_xor(sm2, off);
        m = fmaxf(mx2, mo); sm2 = sm2 * __expf(mx2 - m) + so * __expf(mo - m); mx2 = m;
        mo = __shfl_xor(mx3, off); so = __shfl_xor(sm3, off);
        m = fmaxf(mx3, mo); sm3 = sm3 * __expf(mx3 - m) + so * __expf(mo - m); mx3 = m;
    }
    const float inv0 = 1.f / (sm0 + 1e-16f), inv1 = 1.f / (sm1 + 1e-16f);
    const float inv2 = 1.f / (sm2 + 1e-16f), inv3 = 1.f / (sm3 + 1e-16f);

    // ---- phase 2: weighted aggregation; lane owns channels {lane, lane+64} ----
    const int h0 = lane >> 5;                    // head of channel `lane` (0/1)
    const float adA = h0 ? ad4.y : ad4.x, adB = h0 ? ad4.w : ad4.z;
    const float mA  = h0 ? mx1 : mx0,    mB  = h0 ? mx3 : mx2;
    const float iA  = h0 ? inv1 : inv0,  iB  = h0 ? inv3 : inv2;
    float acc0 = 0.f, acc1 = 0.f;
    for (int j = lo; j < hi; ++j) {
        int s = col[j];
        float aA = a1s[s * 4 + h0] + adA;
        float aB = a1s[s * 4 + 2 + h0] + adB;
        aA = aA > 0.f ? aA : NEG_ATT * aA;
        aB = aB > 0.f ? aB : NEG_ATT * aB;
        float alA = __expf(aA - mA) * iA;
        float alB = __expf(aB - mB) * iB;
        acc0 = fmaf(h1[(long)s * 128 + lane], alA, acc0);
        acc1 = fmaf(h1[(long)s * 128 + 64 + lane], alB, acc1);
    }
    g1[(long)d * 128 + lane]      = acc0 + b1[lane];
    g1[(long)d * 128 + 64 + lane] = acc1 + b1[64 + lane];
}

// ============================ GEMM2 fused: h2 = leaky(g1) @ W2, + a2s/a2d ============================
__global__ void k_gemm2(const float* __restrict__ g1, const float* __restrict__ W2,
                        const float* __restrict__ a2srcv, const float* __restrict__ a2dstv,
                        float* __restrict__ h2, float* __restrict__ a2s, float* __restrict__ a2d,
                        int N) {
    __shared__ float xs[128];
    const int n = blockIdx.x, j = threadIdx.x;   // 64 threads
    for (int t = j; t < 128; t += 64) {
        float v = g1[(long)n * 128 + t];
        xs[t] = v > 0.f ? v : NEG_ACT * v;
    }
    __syncthreads();
    float acc = 0.f;
    for (int k = 0; k < 128; ++k) acc = fmaf(xs[k], W2[k * 64 + j], acc);
    h2[(long)n * 64 + j] = acc;
    float vs = acc * a2srcv[j], vd = acc * a2dstv[j];
    #pragma unroll
    for (int m = 32; m >= 1; m >>= 1) {
        vs += __shfl_xor(vs, m);
        vd += __shfl_xor(vd, m);
    }
    if (j == 0) { a2s[n] = vs; a2d[n] = vd; }
}

// ============================ layer-2 fused softmax+aggregate, one wave per dst ============================
__global__ void k_aggr2(const int* __restrict__ rowptr, const int* __restrict__ col,
                        const float* __restrict__ h2, const float* __restrict__ a2s,
                        const float* __restrict__ a2d, const float* __restrict__ b2,
                        float* __restrict__ zout, int N) {
    const int wid = (blockIdx.x * blockDim.x + threadIdx.x) >> 6;
    const int lane = threadIdx.x & 63;
    if (wid >= N) return;
    const int d = wid;
    const int lo = rowptr[d], hi = rowptr[d + 1];
    const float ad = a2d[d];

    float mx = NEG_BIG, sm = 0.f;
    for (int j = lo + lane; j < hi; j += 64) {
        int s = col[j];
        float a = a2s[s] + ad;
        a = a > 0.f ? a : NEG_ATT * a;
        float m = fmaxf(mx, a);
        sm = sm * __expf(mx - m) + __expf(a - m);
        mx = m;
    }
    #pragma unroll
    for (int off = 32; off >= 1; off >>= 1) {
        float mo = __shfl_xor(mx, off), so = __shfl_xor(sm, off);
        float m = fmaxf(mx, mo);
        sm = sm * __expf(mx - m) + so * __expf(mo - m);
        mx = m;
    }
    const float inv = 1.f / (sm + 1e-16f);

    float acc = 0.f;
    for (int j = lo; j < hi; ++j) {
        int s = col[j];
        float a = a2s[s] + ad;
        a = a > 0.f ? a : NEG_ATT * a;
        float al = __expf(a - mx) * inv;
        acc = fmaf(h2[(long)s * 64 + lane], al, acc);
    }
    zout[(long)d * 64 + lane] = acc + b2[lane];
}

// ============================ decoder: per original edge, [128]->[32]->1 MLP ============================
__global__ void k_dec(const int* __restrict__ ei, int E, const float* __restrict__ z,
                      const float* __restrict__ Wd1, const float* __restrict__ bd1,
                      const float* __restrict__ Wd2, const float* __restrict__ bd2,
                      float* __restrict__ pred) {
    __shared__ float fs[8][128];
    const int g = threadIdx.x >> 5, j = threadIdx.x & 31;
    long e = (long)blockIdx.x * 8 + g;
    bool valid = (e < E);
    if (valid) {
        int s = ei[e], d = ei[E + e];
        fs[g][j]      = z[(long)s * 64 + j];
        fs[g][32 + j] = z[(long)s * 64 + 32 + j];
        fs[g][64 + j] = z[(long)d * 64 + j];
        fs[g][96 + j] = z[(long)d * 64 + 32 + j];
    }
    __syncthreads();
    if (!valid) return;
    float acc = bd1[j];
    for (int k = 0; k < 128; ++k) acc = fmaf(fs[g][k], Wd1[k * 32 + j], acc);
    acc = acc > 0.f ? acc : 0.f;
    float p = acc * Wd2[j];
    #pragma unroll
    for (int m = 16; m >= 1; m >>= 1) p += __shfl_xor(p, m, 32);
    if (j == 0) pred[e] = p + bd2[0];
}

// ============================ launch ============================
extern "C" void kernel_launch(void* const* d_in, const int* in_sizes, int n_in,
                              void* d_out, int out_size, void* d_ws, size_t ws_size,
                              hipStream_t stream) {
    const float* x    = (const float*)d_in[0];
    const int*   ei   = (const int*)d_in[1];
    const float* W1   = (const float*)d_in[2];
    const float* a1sw = (const float*)d_in[3];
    const float* a1dw = (const float*)d_in[4];
    const float* b1   = (const float*)d_in[5];
    const float* W2   = (const float*)d_in[6];
    const float* a2sw = (const float*)d_in[7];
    const float* a2dw = (const float*)d_in[8];
    const float* b2   = (const float*)d_in[9];
    const float* Wd1  = (const float*)d_in[10];
    const float* bd1  = (const float*)d_in[11];
    const float* Wd2  = (const float*)d_in[12];
    const float* bd2  = (const float*)d_in[13];

    const int N = in_sizes[0] / 128;        // 50000
    const int E = in_sizes[1] / 2;          // 1600000
    const int E2 = E + N;

    float* pred = (float*)d_out;            // [E]
    float* zout = (float*)d_out + E;        // [N,64]

    // workspace layout
    float* W = (float*)d_ws;
    size_t o = 0;
    float* h1  = W + o; o += (size_t)N * 128;
    float* g1  = W + o; o += (size_t)N * 128;
    float* h2  = W + o; o += (size_t)N * 64;
    float* a1s = W + o; o += (size_t)N * 4;
    float* a1d = W + o; o += (size_t)N * 4;
    float* a2s = W + o; o += (size_t)N;
    float* a2d = W + o; o += (size_t)N;
    int* counts = (int*)(W + o); o += (size_t)N;
    int* rowptr = (int*)(W + o); o += (size_t)N + 1;
    int* cursor = (int*)(W + o); o += (size_t)N;
    int* col    = (int*)(W + o); o += (size_t)E2;
    if (ws_size < o * sizeof(float)) return;

    const int TB = 256;
    const int gE = (E2 + TB - 1) / TB;

    // CSR build
    k_zero<<<(N + TB - 1) / TB, TB, 0, stream>>>(counts, N);
    k_count<<<gE, TB, 0, stream>>>(ei, E, N, counts);
    k_scan<<<1, 1024, 0, stream>>>(counts, N, rowptr, cursor);
    k_scatter<<<gE, TB, 0, stream>>>(ei, E, N, cursor, col);

    // layer 1
    k_gemm1<<<(N + 7) / 8, 128, 0, stream>>>(x, W1, h1, N);
    k_att1<<<N, 128, 0, stream>>>(h1, a1sw, a1dw, a1s, a1d, N);
    k_aggr1<<<(N + 3) / 4, 256, 0, stream>>>(rowptr, col, h1, a1s, a1d, b1, g1, N);

    // layer 2
    k_gemm2<<<N, 64, 0, stream>>>(g1, W2, a2sw, a2dw, h2, a2s, a2d, N);
    k_aggr2<<<(N + 3) / 4, 256, 0, stream>>>(rowptr, col, h2, a2s, a2d, b2, zout, N);

    // decoder
    k_dec<<<(E + 7) / 8, 256, 0, stream>>>(ei, E, zout, Wd1, bd1, Wd2, bd2, pred);
}

// Round 3
// 844.585 us; speedup vs baseline: 6.9283x; 1.7876x over previous
//
#include <hip/hip_runtime.h>
#include <hip/hip_bf16.h>
#include <math.h>

#define NEG_ATT 0.2f
#define NEG_ACT 0.01f
#define NEG_BIG -1e30f

// ============================ CSR build ============================
__global__ void k_zero(int* __restrict__ counts, int N) {
    int i = blockIdx.x * blockDim.x + threadIdx.x;
    if (i < N) counts[i] = 0;
}

__global__ void k_count(const int* __restrict__ ei, int E, int N, int* __restrict__ counts) {
    int e = blockIdx.x * blockDim.x + threadIdx.x;
    if (e >= E + N) return;
    int d = (e < E) ? ei[E + e] : e - E;
    atomicAdd(&counts[d], 1);
}

// single-block 1024-thread exclusive scan over counts[0..N) -> rowptr[0..N], cursor copy
__global__ void k_scan(const int* __restrict__ counts, int N,
                       int* __restrict__ rowptr, int* __restrict__ cursor) {
    __shared__ int ps[1024];
    const int t = threadIdx.x;
    const int C = (N + 1023) >> 10;
    const int lo = t * C, hi = min(lo + C, N);
    int sum = 0;
    for (int i = lo; i < hi; ++i) sum += counts[i];
    ps[t] = sum;
    __syncthreads();
    for (int off = 1; off < 1024; off <<= 1) {
        int v = (t >= off) ? ps[t - off] : 0;
        __syncthreads();
        ps[t] += v;
        __syncthreads();
    }
    int run = ps[t] - sum;   // exclusive prefix
    for (int i = lo; i < hi; ++i) {
        rowptr[i] = run; cursor[i] = run;
        run += counts[i];
    }
    if (t == 1023) rowptr[N] = ps[1023];
}

__global__ void k_scatter(const int* __restrict__ ei, int E, int N,
                          int* __restrict__ cursor, int* __restrict__ col) {
    int e = blockIdx.x * blockDim.x + threadIdx.x;
    if (e >= E + N) return;
    int s, d;
    if (e < E) { s = ei[e]; d = ei[E + e]; } else { s = d = e - E; }
    int pos = atomicAdd(&cursor[d], 1);
    col[pos] = s;
}

// ============================ GEMM1: h1 = x @ W1  [N,128]x[128,128] ============================
__global__ void k_gemm1(const float* __restrict__ x, const float* __restrict__ W1,
                        float* __restrict__ h1, int N) {
    __shared__ float xs[8][128];
    const int j = threadIdx.x;
    const int row0 = blockIdx.x * 8;
    #pragma unroll
    for (int r = 0; r < 8; ++r) {
        int n = row0 + r;
        xs[r][j] = (n < N) ? x[(long)n * 128 + j] : 0.f;
    }
    __syncthreads();
    float acc[8];
    #pragma unroll
    for (int r = 0; r < 8; ++r) acc[r] = 0.f;
    for (int k = 0; k < 128; ++k) {
        float w = W1[k * 128 + j];
        #pragma unroll
        for (int r = 0; r < 8; ++r) acc[r] = fmaf(xs[r][k], w, acc[r]);
    }
    #pragma unroll
    for (int r = 0; r < 8; ++r) {
        int n = row0 + r;
        if (n < N) h1[(long)n * 128 + j] = acc[r];
    }
}

// ============================ attention coeffs layer 1 ============================
__global__ void k_att1(const float* __restrict__ h1, const float* __restrict__ as,
                       const float* __restrict__ ad,
                       float* __restrict__ a1s, float* __restrict__ a1d, int N) {
    const int n = blockIdx.x, j = threadIdx.x;   // 128 threads
    float h = h1[(long)n * 128 + j];
    float vs = h * as[j], vd = h * ad[j];
    #pragma unroll
    for (int m = 16; m >= 1; m >>= 1) {
        vs += __shfl_xor(vs, m, 32);
        vd += __shfl_xor(vd, m, 32);
    }
    if ((j & 31) == 0) { a1s[n * 4 + (j >> 5)] = vs; a1d[n * 4 + (j >> 5)] = vd; }
}

// ============================ layer-1 fused softmax+aggregate, one wave per dst ============================
__global__ void k_aggr1(const int* __restrict__ rowptr, const int* __restrict__ col,
                        const float* __restrict__ h1, const float* __restrict__ a1s,
                        const float* __restrict__ a1d, const float* __restrict__ b1,
                        float* __restrict__ g1, int N) {
    const int wid = (blockIdx.x * blockDim.x + threadIdx.x) >> 6;
    const int lane = threadIdx.x & 63;
    if (wid >= N) return;
    const int d = wid;
    const int lo = rowptr[d], hi = rowptr[d + 1];
    const float4 ad4 = *(const float4*)&a1d[d * 4];

    // ---- phase 1: online softmax stats per head (strided over edges) ----
    float mx0 = NEG_BIG, mx1 = NEG_BIG, mx2 = NEG_BIG, mx3 = NEG_BIG;
    float sm0 = 0.f, sm1 = 0.f, sm2 = 0.f, sm3 = 0.f;
    for (int j = lo + lane; j < hi; j += 64) {
        int s = col[j];
        float4 as4 = *(const float4*)&a1s[s * 4];
        float a0 = as4.x + ad4.x, a1 = as4.y + ad4.y, a2 = as4.z + ad4.z, a3 = as4.w + ad4.w;
        a0 = a0 > 0.f ? a0 : NEG_ATT * a0;
        a1 = a1 > 0.f ? a1 : NEG_ATT * a1;
        a2 = a2 > 0.f ? a2 : NEG_ATT * a2;
        a3 = a3 > 0.f ? a3 : NEG_ATT * a3;
        float m;
        m = fmaxf(mx0, a0); sm0 = sm0 * __expf(mx0 - m) + __expf(a0 - m); mx0 = m;
        m = fmaxf(mx1, a1); sm1 = sm1 * __expf(mx1 - m) + __expf(a1 - m); mx1 = m;
        m = fmaxf(mx2, a2); sm2 = sm2 * __expf(mx2 - m) + __expf(a2 - m); mx2 = m;
        m = fmaxf(mx3, a3); sm3 = sm3 * __expf(mx3 - m) + __expf(a3 - m); mx3 = m;
    }
    // ---- wave-reduce (mx, sm) pairs ----
    #pragma unroll
    for (int off = 32; off >= 1; off >>= 1) {
        float mo, so, m;
        mo = __shfl_xor(mx0, off); so = __shfl_xor(sm0, off);
        m = fmaxf(mx0, mo); sm0 = sm0 * __expf(mx0 - m) + so * __expf(mo - m); mx0 = m;
        mo = __shfl_xor(mx1, off); so = __shfl_xor(sm1, off);
        m = fmaxf(mx1, mo); sm1 = sm1 * __expf(mx1 - m) + so * __expf(mo - m); mx1 = m;
        mo = __shfl_xor(mx2, off); so = __shfl_xor(sm2, off);
        m = fmaxf(mx2, mo); sm2 = sm2 * __expf(mx2 - m) + so * __expf(mo - m); mx2 = m;
        mo = __shfl_xor(mx3, off); so = __shfl_xor(sm3, off);
        m = fmaxf(mx3, mo); sm3 = sm3 * __expf(mx3 - m) + so * __expf(mo - m); mx3 = m;
    }
    const float inv0 = 1.f / (sm0 + 1e-16f), inv1 = 1.f / (sm1 + 1e-16f);
    const float inv2 = 1.f / (sm2 + 1e-16f), inv3 = 1.f / (sm3 + 1e-16f);

    // ---- phase 2: weighted aggregation; lane owns channels {lane, lane+64} ----
    const int h0 = lane >> 5;                    // head of channel `lane` (0/1)
    const float adA = h0 ? ad4.y : ad4.x, adB = h0 ? ad4.w : ad4.z;
    const float mA  = h0 ? mx1 : mx0,    mB  = h0 ? mx3 : mx2;
    const float iA  = h0 ? inv1 : inv0,  iB  = h0 ? inv3 : inv2;
    float acc0 = 0.f, acc1 = 0.f;
    for (int j = lo; j < hi; ++j) {
        int s = col[j];
        float aA = a1s[s * 4 + h0] + adA;
        float aB = a1s[s * 4 + 2 + h0] + adB;
        aA = aA > 0.f ? aA : NEG_ATT * aA;
        aB = aB > 0.f ? aB : NEG_ATT * aB;
        float alA = __expf(aA - mA) * iA;
        float alB = __expf(aB - mB) * iB;
        acc0 = fmaf(h1[(long)s * 128 + lane], alA, acc0);
        acc1 = fmaf(h1[(long)s * 128 + 64 + lane], alB, acc1);
    }
    g1[(long)d * 128 + lane]      = acc0 + b1[lane];
    g1[(long)d * 128 + 64 + lane] = acc1 + b1[64 + lane];
}

// ============================ GEMM2 fused: h2 = leaky(g1) @ W2, + a2s/a2d ============================
__global__ void k_gemm2(const float* __restrict__ g1, const float* __restrict__ W2,
                        const float* __restrict__ a2srcv, const float* __restrict__ a2dstv,
                        float* __restrict__ h2, float* __restrict__ a2s, float* __restrict__ a2d,
                        int N) {
    __shared__ float xs[128];
    const int n = blockIdx.x, j = threadIdx.x;   // 64 threads
    for (int t = j; t < 128; t += 64) {
        float v = g1[(long)n * 128 + t];
        xs[t] = v > 0.f ? v : NEG_ACT * v;
    }
    __syncthreads();
    float acc = 0.f;
    for (int k = 0; k < 128; ++k) acc = fmaf(xs[k], W2[k * 64 + j], acc);
    h2[(long)n * 64 + j] = acc;
    float vs = acc * a2srcv[j], vd = acc * a2dstv[j];
    #pragma unroll
    for (int m = 32; m >= 1; m >>= 1) {
        vs += __shfl_xor(vs, m);
        vd += __shfl_xor(vd, m);
    }
    if (j == 0) { a2s[n] = vs; a2d[n] = vd; }
}

// ============================ layer-2 fused softmax+aggregate, one wave per dst ============================
__global__ void k_aggr2(const int* __restrict__ rowptr, const int* __restrict__ col,
                        const float* __restrict__ h2, const float* __restrict__ a2s,
                        const float* __restrict__ a2d, const float* __restrict__ b2,
                        float* __restrict__ zout, int N) {
    const int wid = (blockIdx.x * blockDim.x + threadIdx.x) >> 6;
    const int lane = threadIdx.x & 63;
    if (wid >= N) return;
    const int d = wid;
    const int lo = rowptr[d], hi = rowptr[d + 1];
    const float ad = a2d[d];

    float mx = NEG_BIG, sm = 0.f;
    for (int j = lo + lane; j < hi; j += 64) {
        int s = col[j];
        float a = a2s[s] + ad;
        a = a > 0.f ? a : NEG_ATT * a;
        float m = fmaxf(mx, a);
        sm = sm * __expf(mx - m) + __expf(a - m);
        mx = m;
    }
    #pragma unroll
    for (int off = 32; off >= 1; off >>= 1) {
        float mo = __shfl_xor(mx, off), so = __shfl_xor(sm, off);
        float m = fmaxf(mx, mo);
        sm = sm * __expf(mx - m) + so * __expf(mo - m);
        mx = m;
    }
    const float inv = 1.f / (sm + 1e-16f);

    float acc = 0.f;
    for (int j = lo; j < hi; ++j) {
        int s = col[j];
        float a = a2s[s] + ad;
        a = a > 0.f ? a : NEG_ATT * a;
        float al = __expf(a - mx) * inv;
        acc = fmaf(h2[(long)s * 64 + lane], al, acc);
    }
    zout[(long)d * 64 + lane] = acc + b2[lane];
}

// ============================ decoder node-level precompute ============================
// u[n][j] = sum_k z[n][k]*Wd1[k][j] + bd1[j]   (src half of Wd1)
// v[n][j] = sum_k z[n][k]*Wd1[64+k][j]          (dst half)
__global__ void k_uv(const float* __restrict__ z, const float* __restrict__ Wd1,
                     const float* __restrict__ bd1,
                     float* __restrict__ u, float* __restrict__ v, int N) {
    __shared__ float zs[4][64];
    const int w = threadIdx.x >> 6;              // node slot 0..3
    const int lane = threadIdx.x & 63;
    const int n = blockIdx.x * 4 + w;
    if (n < N) zs[w][lane] = z[(long)n * 64 + lane];
    __syncthreads();
    if (n >= N) return;
    const int jj = lane & 31;
    const int base = (lane < 32) ? 0 : 64 * 32;  // top half -> u, bottom -> v
    float acc = (lane < 32) ? bd1[jj] : 0.f;
    #pragma unroll
    for (int k = 0; k < 64; ++k)
        acc = fmaf(zs[w][k], Wd1[base + k * 32 + jj], acc);
    if (lane < 32) u[(long)n * 32 + jj] = acc;
    else           v[(long)n * 32 + jj] = acc;
}

// ============================ decoder per-edge: relu(u[s]+v[d]) . Wd2 + bd2 ============================
__global__ void k_dec2(const int* __restrict__ ei, int E,
                       const float* __restrict__ u, const float* __restrict__ v,
                       const float* __restrict__ Wd2, const float* __restrict__ bd2,
                       float* __restrict__ pred) {
    long e = (long)blockIdx.x * blockDim.x + threadIdx.x;
    if (e >= E) return;
    int s = ei[e], d = ei[E + e];
    const float4* us = (const float4*)&u[(long)s * 32];
    const float4* vd = (const float4*)&v[(long)d * 32];
    float p = 0.f;
    #pragma unroll
    for (int c = 0; c < 8; ++c) {
        float4 a = us[c], b = vd[c];
        float h0 = a.x + b.x, h1 = a.y + b.y, h2 = a.z + b.z, h3 = a.w + b.w;
        h0 = h0 > 0.f ? h0 : 0.f;
        h1 = h1 > 0.f ? h1 : 0.f;
        h2 = h2 > 0.f ? h2 : 0.f;
        h3 = h3 > 0.f ? h3 : 0.f;
        p = fmaf(h0, Wd2[c * 4 + 0], p);
        p = fmaf(h1, Wd2[c * 4 + 1], p);
        p = fmaf(h2, Wd2[c * 4 + 2], p);
        p = fmaf(h3, Wd2[c * 4 + 3], p);
    }
    pred[e] = p + bd2[0];
}

// ============================ launch ============================
extern "C" void kernel_launch(void* const* d_in, const int* in_sizes, int n_in,
                              void* d_out, int out_size, void* d_ws, size_t ws_size,
                              hipStream_t stream) {
    const float* x    = (const float*)d_in[0];
    const int*   ei   = (const int*)d_in[1];
    const float* W1   = (const float*)d_in[2];
    const float* a1sw = (const float*)d_in[3];
    const float* a1dw = (const float*)d_in[4];
    const float* b1   = (const float*)d_in[5];
    const float* W2   = (const float*)d_in[6];
    const float* a2sw = (const float*)d_in[7];
    const float* a2dw = (const float*)d_in[8];
    const float* b2   = (const float*)d_in[9];
    const float* Wd1  = (const float*)d_in[10];
    const float* bd1  = (const float*)d_in[11];
    const float* Wd2  = (const float*)d_in[12];
    const float* bd2  = (const float*)d_in[13];

    const int N = in_sizes[0] / 128;        // 50000
    const int E = in_sizes[1] / 2;          // 1600000
    const int E2 = E + N;

    float* pred = (float*)d_out;            // [E]
    float* zout = (float*)d_out + E;        // [N,64]

    // workspace layout
    float* W = (float*)d_ws;
    size_t o = 0;
    float* h1  = W + o; o += (size_t)N * 128;
    float* g1  = W + o; o += (size_t)N * 128;
    float* h2  = W + o; o += (size_t)N * 64;
    float* uu  = W + o; o += (size_t)N * 32;
    float* vv  = W + o; o += (size_t)N * 32;
    float* a1s = W + o; o += (size_t)N * 4;
    float* a1d = W + o; o += (size_t)N * 4;
    float* a2s = W + o; o += (size_t)N;
    float* a2d = W + o; o += (size_t)N;
    int* counts = (int*)(W + o); o += (size_t)N;
    int* rowptr = (int*)(W + o); o += (size_t)N + 1;
    int* cursor = (int*)(W + o); o += (size_t)N;
    int* col    = (int*)(W + o); o += (size_t)E2;
    if (ws_size < o * sizeof(float)) return;

    const int TB = 256;
    const int gE = (E2 + TB - 1) / TB;

    // CSR build
    k_zero<<<(N + TB - 1) / TB, TB, 0, stream>>>(counts, N);
    k_count<<<gE, TB, 0, stream>>>(ei, E, N, counts);
    k_scan<<<1, 1024, 0, stream>>>(counts, N, rowptr, cursor);
    k_scatter<<<gE, TB, 0, stream>>>(ei, E, N, cursor, col);

    // layer 1
    k_gemm1<<<(N + 7) / 8, 128, 0, stream>>>(x, W1, h1, N);
    k_att1<<<N, 128, 0, stream>>>(h1, a1sw, a1dw, a1s, a1d, N);
    k_aggr1<<<(N + 3) / 4, 256, 0, stream>>>(rowptr, col, h1, a1s, a1d, b1, g1, N);

    // layer 2
    k_gemm2<<<N, 64, 0, stream>>>(g1, W2, a2sw, a2dw, h2, a2s, a2d, N);
    k_aggr2<<<(N + 3) / 4, 256, 0, stream>>>(rowptr, col, h2, a2s, a2d, b2, zout, N);

    // decoder (split: first layer is linear over the concat)
    k_uv<<<(N + 3) / 4, 256, 0, stream>>>(zout, Wd1, bd1, uu, vv, N);
    k_dec2<<<(E + TB - 1) / TB, TB, 0, stream>>>(ei, E, uu, vv, Wd2, bd2, pred);
}

// Round 4
// 643.696 us; speedup vs baseline: 9.0906x; 1.3121x over previous
//
#include <hip/hip_runtime.h>
#include <hip/hip_bf16.h>
#include <math.h>

#define NEG_ATT 0.2f
#define NEG_ACT 0.01f
#define NEG_BIG -1e30f

// ============================ CSR build ============================
__global__ void k_zero(int* __restrict__ counts, int N) {
    int i = blockIdx.x * blockDim.x + threadIdx.x;
    if (i < N) counts[i] = 0;
}

__global__ void k_count(const int* __restrict__ ei, int E, int N, int* __restrict__ counts) {
    int e = blockIdx.x * blockDim.x + threadIdx.x;
    if (e >= E + N) return;
    int d = (e < E) ? ei[E + e] : e - E;
    atomicAdd(&counts[d], 1);
}

// single-block 1024-thread exclusive scan over counts[0..N) -> rowptr[0..N], cursor copy
__global__ void k_scan(const int* __restrict__ counts, int N,
                       int* __restrict__ rowptr, int* __restrict__ cursor) {
    __shared__ int ps[1024];
    const int t = threadIdx.x;
    const int C = (N + 1023) >> 10;
    const int lo = t * C, hi = min(lo + C, N);
    int sum = 0;
    for (int i = lo; i < hi; ++i) sum += counts[i];
    ps[t] = sum;
    __syncthreads();
    for (int off = 1; off < 1024; off <<= 1) {
        int v = (t >= off) ? ps[t - off] : 0;
        __syncthreads();
        ps[t] += v;
        __syncthreads();
    }
    int run = ps[t] - sum;   // exclusive prefix
    for (int i = lo; i < hi; ++i) {
        rowptr[i] = run; cursor[i] = run;
        run += counts[i];
    }
    if (t == 1023) rowptr[N] = ps[1023];
}

__global__ void k_scatter(const int* __restrict__ ei, int E, int N,
                          int* __restrict__ cursor, int* __restrict__ col) {
    int e = blockIdx.x * blockDim.x + threadIdx.x;
    if (e >= E + N) return;
    int s, d;
    if (e < E) { s = ei[e]; d = ei[E + e]; } else { s = d = e - E; }
    int pos = atomicAdd(&cursor[d], 1);
    col[pos] = s;
}

// ============================ GEMM1: h1 = x @ W1  [N,128]x[128,128] ============================
__global__ void k_gemm1(const float* __restrict__ x, const float* __restrict__ W1,
                        float* __restrict__ h1, int N) {
    __shared__ float xs[8][128];
    const int j = threadIdx.x;
    const int row0 = blockIdx.x * 8;
    #pragma unroll
    for (int r = 0; r < 8; ++r) {
        int n = row0 + r;
        xs[r][j] = (n < N) ? x[(long)n * 128 + j] : 0.f;
    }
    __syncthreads();
    float acc[8];
    #pragma unroll
    for (int r = 0; r < 8; ++r) acc[r] = 0.f;
    for (int k = 0; k < 128; ++k) {
        float w = W1[k * 128 + j];
        #pragma unroll
        for (int r = 0; r < 8; ++r) acc[r] = fmaf(xs[r][k], w, acc[r]);
    }
    #pragma unroll
    for (int r = 0; r < 8; ++r) {
        int n = row0 + r;
        if (n < N) h1[(long)n * 128 + j] = acc[r];
    }
}

// ============================ attention coeffs layer 1 ============================
__global__ void k_att1(const float* __restrict__ h1, const float* __restrict__ as,
                       const float* __restrict__ ad,
                       float* __restrict__ a1s, float* __restrict__ a1d, int N) {
    const int n = blockIdx.x, j = threadIdx.x;   // 128 threads
    float h = h1[(long)n * 128 + j];
    float vs = h * as[j], vd = h * ad[j];
    #pragma unroll
    for (int m = 16; m >= 1; m >>= 1) {
        vs += __shfl_xor(vs, m, 32);
        vd += __shfl_xor(vd, m, 32);
    }
    if ((j & 31) == 0) { a1s[n * 4 + (j >> 5)] = vs; a1d[n * 4 + (j >> 5)] = vd; }
}

// ============================ layer-1 fused softmax+aggregate, one wave per dst ============================
// phase 2 chunked: per 64-edge chunk, lane computes its edge's 4 alphas into LDS,
// then the whole wave does a pure FMA+gather loop with LDS-broadcast alphas.
__global__ void k_aggr1(const int* __restrict__ rowptr, const int* __restrict__ col,
                        const float* __restrict__ h1, const float* __restrict__ a1s,
                        const float* __restrict__ a1d, const float* __restrict__ b1,
                        float* __restrict__ g1, int N) {
    __shared__ float als[4][64][4];
    __shared__ int   scol[4][64];
    const int w = threadIdx.x >> 6;
    const int lane = threadIdx.x & 63;
    const int d = blockIdx.x * 4 + w;
    if (d >= N) return;
    const int lo = rowptr[d], hi = rowptr[d + 1];
    const float4 ad4 = *(const float4*)&a1d[d * 4];

    // ---- phase 1: online softmax stats per head (strided over edges) ----
    float mx0 = NEG_BIG, mx1 = NEG_BIG, mx2 = NEG_BIG, mx3 = NEG_BIG;
    float sm0 = 0.f, sm1 = 0.f, sm2 = 0.f, sm3 = 0.f;
    for (int j = lo + lane; j < hi; j += 64) {
        int s = col[j];
        float4 as4 = *(const float4*)&a1s[s * 4];
        float a0 = as4.x + ad4.x, a1 = as4.y + ad4.y, a2 = as4.z + ad4.z, a3 = as4.w + ad4.w;
        a0 = a0 > 0.f ? a0 : NEG_ATT * a0;
        a1 = a1 > 0.f ? a1 : NEG_ATT * a1;
        a2 = a2 > 0.f ? a2 : NEG_ATT * a2;
        a3 = a3 > 0.f ? a3 : NEG_ATT * a3;
        float m;
        m = fmaxf(mx0, a0); sm0 = sm0 * __expf(mx0 - m) + __expf(a0 - m); mx0 = m;
        m = fmaxf(mx1, a1); sm1 = sm1 * __expf(mx1 - m) + __expf(a1 - m); mx1 = m;
        m = fmaxf(mx2, a2); sm2 = sm2 * __expf(mx2 - m) + __expf(a2 - m); mx2 = m;
        m = fmaxf(mx3, a3); sm3 = sm3 * __expf(mx3 - m) + __expf(a3 - m); mx3 = m;
    }
    #pragma unroll
    for (int off = 32; off >= 1; off >>= 1) {
        float mo, so, m;
        mo = __shfl_xor(mx0, off); so = __shfl_xor(sm0, off);
        m = fmaxf(mx0, mo); sm0 = sm0 * __expf(mx0 - m) + so * __expf(mo - m); mx0 = m;
        mo = __shfl_xor(mx1, off); so = __shfl_xor(sm1, off);
        m = fmaxf(mx1, mo); sm1 = sm1 * __expf(mx1 - m) + so * __expf(mo - m); mx1 = m;
        mo = __shfl_xor(mx2, off); so = __shfl_xor(sm2, off);
        m = fmaxf(mx2, mo); sm2 = sm2 * __expf(mx2 - m) + so * __expf(mo - m); mx2 = m;
        mo = __shfl_xor(mx3, off); so = __shfl_xor(sm3, off);
        m = fmaxf(mx3, mo); sm3 = sm3 * __expf(mx3 - m) + so * __expf(mo - m); mx3 = m;
    }
    const float inv0 = 1.f / (sm0 + 1e-16f), inv1 = 1.f / (sm1 + 1e-16f);
    const float inv2 = 1.f / (sm2 + 1e-16f), inv3 = 1.f / (sm3 + 1e-16f);

    // ---- phase 2: chunked ----
    const int h0 = lane >> 5;                    // head of channel `lane` (0/1)
    float acc0 = 0.f, acc1 = 0.f;
    for (int base = lo; base < hi; base += 64) {
        const int cnt = min(64, hi - base);
        if (lane < cnt) {
            int s = col[base + lane];
            float4 as4 = *(const float4*)&a1s[s * 4];
            float a0 = as4.x + ad4.x, a1 = as4.y + ad4.y, a2 = as4.z + ad4.z, a3 = as4.w + ad4.w;
            a0 = a0 > 0.f ? a0 : NEG_ATT * a0;
            a1 = a1 > 0.f ? a1 : NEG_ATT * a1;
            a2 = a2 > 0.f ? a2 : NEG_ATT * a2;
            a3 = a3 > 0.f ? a3 : NEG_ATT * a3;
            float4 al;
            al.x = __expf(a0 - mx0) * inv0;
            al.y = __expf(a1 - mx1) * inv1;
            al.z = __expf(a2 - mx2) * inv2;
            al.w = __expf(a3 - mx3) * inv3;
            *(float4*)&als[w][lane][0] = al;
            scol[w][lane] = s;
        }
        __builtin_amdgcn_wave_barrier();   // compiler fence; DS pipe is in-order per wave
        for (int t = 0; t < cnt; ++t) {
            int s = scol[w][t];
            float alA = als[w][t][h0];
            float alB = als[w][t][2 + h0];
            acc0 = fmaf(h1[(long)s * 128 + lane], alA, acc0);
            acc1 = fmaf(h1[(long)s * 128 + 64 + lane], alB, acc1);
        }
        __builtin_amdgcn_wave_barrier();   // WAR fence before next chunk's stores
    }
    g1[(long)d * 128 + lane]      = acc0 + b1[lane];
    g1[(long)d * 128 + 64 + lane] = acc1 + b1[64 + lane];
}

// ============================ GEMM2 fused: h2 = leaky(g1) @ W2, + a2s/a2d ============================
__global__ void k_gemm2(const float* __restrict__ g1, const float* __restrict__ W2,
                        const float* __restrict__ a2srcv, const float* __restrict__ a2dstv,
                        float* __restrict__ h2, float* __restrict__ a2s, float* __restrict__ a2d,
                        int N) {
    __shared__ float xs[128];
    const int n = blockIdx.x, j = threadIdx.x;   // 64 threads
    for (int t = j; t < 128; t += 64) {
        float v = g1[(long)n * 128 + t];
        xs[t] = v > 0.f ? v : NEG_ACT * v;
    }
    __syncthreads();
    float acc = 0.f;
    for (int k = 0; k < 128; ++k) acc = fmaf(xs[k], W2[k * 64 + j], acc);
    h2[(long)n * 64 + j] = acc;
    float vs = acc * a2srcv[j], vd = acc * a2dstv[j];
    #pragma unroll
    for (int m = 32; m >= 1; m >>= 1) {
        vs += __shfl_xor(vs, m);
        vd += __shfl_xor(vd, m);
    }
    if (j == 0) { a2s[n] = vs; a2d[n] = vd; }
}

// ============================ layer-2 fused softmax+aggregate, one wave per dst ============================
__global__ void k_aggr2(const int* __restrict__ rowptr, const int* __restrict__ col,
                        const float* __restrict__ h2, const float* __restrict__ a2s,
                        const float* __restrict__ a2d, const float* __restrict__ b2,
                        float* __restrict__ zout, int N) {
    __shared__ float als[4][64];
    __shared__ int   scol[4][64];
    const int w = threadIdx.x >> 6;
    const int lane = threadIdx.x & 63;
    const int d = blockIdx.x * 4 + w;
    if (d >= N) return;
    const int lo = rowptr[d], hi = rowptr[d + 1];
    const float ad = a2d[d];

    float mx = NEG_BIG, sm = 0.f;
    for (int j = lo + lane; j < hi; j += 64) {
        int s = col[j];
        float a = a2s[s] + ad;
        a = a > 0.f ? a : NEG_ATT * a;
        float m = fmaxf(mx, a);
        sm = sm * __expf(mx - m) + __expf(a - m);
        mx = m;
    }
    #pragma unroll
    for (int off = 32; off >= 1; off >>= 1) {
        float mo = __shfl_xor(mx, off), so = __shfl_xor(sm, off);
        float m = fmaxf(mx, mo);
        sm = sm * __expf(mx - m) + so * __expf(mo - m);
        mx = m;
    }
    const float inv = 1.f / (sm + 1e-16f);

    float acc = 0.f;
    for (int base = lo; base < hi; base += 64) {
        const int cnt = min(64, hi - base);
        if (lane < cnt) {
            int s = col[base + lane];
            float a = a2s[s] + ad;
            a = a > 0.f ? a : NEG_ATT * a;
            als[w][lane] = __expf(a - mx) * inv;
            scol[w][lane] = s;
        }
        __builtin_amdgcn_wave_barrier();
        for (int t = 0; t < cnt; ++t) {
            int s = scol[w][t];
            acc = fmaf(h2[(long)s * 64 + lane], als[w][t], acc);
        }
        __builtin_amdgcn_wave_barrier();
    }
    zout[(long)d * 64 + lane] = acc + b2[lane];
}

// ============================ decoder node-level precompute ============================
__global__ void k_uv(const float* __restrict__ z, const float* __restrict__ Wd1,
                     const float* __restrict__ bd1,
                     float* __restrict__ u, float* __restrict__ v, int N) {
    __shared__ float zs[4][64];
    const int w = threadIdx.x >> 6;              // node slot 0..3
    const int lane = threadIdx.x & 63;
    const int n = blockIdx.x * 4 + w;
    if (n < N) zs[w][lane] = z[(long)n * 64 + lane];
    __syncthreads();
    if (n >= N) return;
    const int jj = lane & 31;
    const int base = (lane < 32) ? 0 : 64 * 32;  // top half -> u, bottom -> v
    float acc = (lane < 32) ? bd1[jj] : 0.f;
    #pragma unroll
    for (int k = 0; k < 64; ++k)
        acc = fmaf(zs[w][k], Wd1[base + k * 32 + jj], acc);
    if (lane < 32) u[(long)n * 32 + jj] = acc;
    else           v[(long)n * 32 + jj] = acc;
}

// ============================ decoder per-edge: relu(u[s]+v[d]) . Wd2 + bd2 ============================
// 8 lanes per edge: coalesced 128B row reads, shfl-reduce within the 8-lane group.
__global__ void k_dec2(const int* __restrict__ ei, int E,
                       const float* __restrict__ u, const float* __restrict__ v,
                       const float* __restrict__ Wd2, const float* __restrict__ bd2,
                       float* __restrict__ pred) {
    const int g = threadIdx.x >> 3;      // edge slot 0..31
    const int l = threadIdx.x & 7;       // lane in group
    long e = (long)blockIdx.x * 32 + g;
    if (e >= E) return;
    int s = ei[e], d = ei[E + e];
    float4 a = *(const float4*)&u[(long)s * 32 + l * 4];
    float4 b = *(const float4*)&v[(long)d * 32 + l * 4];
    float4 wv = *(const float4*)&Wd2[l * 4];
    float h0 = fmaxf(a.x + b.x, 0.f);
    float h1 = fmaxf(a.y + b.y, 0.f);
    float h2 = fmaxf(a.z + b.z, 0.f);
    float h3 = fmaxf(a.w + b.w, 0.f);
    float p = h0 * wv.x;
    p = fmaf(h1, wv.y, p);
    p = fmaf(h2, wv.z, p);
    p = fmaf(h3, wv.w, p);
    p += __shfl_xor(p, 1, 8);
    p += __shfl_xor(p, 2, 8);
    p += __shfl_xor(p, 4, 8);
    if (l == 0) pred[e] = p + bd2[0];
}

// ============================ launch ============================
extern "C" void kernel_launch(void* const* d_in, const int* in_sizes, int n_in,
                              void* d_out, int out_size, void* d_ws, size_t ws_size,
                              hipStream_t stream) {
    const float* x    = (const float*)d_in[0];
    const int*   ei   = (const int*)d_in[1];
    const float* W1   = (const float*)d_in[2];
    const float* a1sw = (const float*)d_in[3];
    const float* a1dw = (const float*)d_in[4];
    const float* b1   = (const float*)d_in[5];
    const float* W2   = (const float*)d_in[6];
    const float* a2sw = (const float*)d_in[7];
    const float* a2dw = (const float*)d_in[8];
    const float* b2   = (const float*)d_in[9];
    const float* Wd1  = (const float*)d_in[10];
    const float* bd1  = (const float*)d_in[11];
    const float* Wd2  = (const float*)d_in[12];
    const float* bd2  = (const float*)d_in[13];

    const int N = in_sizes[0] / 128;        // 50000
    const int E = in_sizes[1] / 2;          // 1600000
    const int E2 = E + N;

    float* pred = (float*)d_out;            // [E]
    float* zout = (float*)d_out + E;        // [N,64]

    // workspace layout
    float* W = (float*)d_ws;
    size_t o = 0;
    float* h1  = W + o; o += (size_t)N * 128;
    float* g1  = W + o; o += (size_t)N * 128;
    float* h2  = W + o; o += (size_t)N * 64;
    float* uu  = W + o; o += (size_t)N * 32;
    float* vv  = W + o; o += (size_t)N * 32;
    float* a1s = W + o; o += (size_t)N * 4;
    float* a1d = W + o; o += (size_t)N * 4;
    float* a2s = W + o; o += (size_t)N;
    float* a2d = W + o; o += (size_t)N;
    int* counts = (int*)(W + o); o += (size_t)N;
    int* rowptr = (int*)(W + o); o += (size_t)N + 1;
    int* cursor = (int*)(W + o); o += (size_t)N;
    int* col    = (int*)(W + o); o += (size_t)E2;
    if (ws_size < o * sizeof(float)) return;

    const int TB = 256;
    const int gE = (E2 + TB - 1) / TB;

    // CSR build
    k_zero<<<(N + TB - 1) / TB, TB, 0, stream>>>(counts, N);
    k_count<<<gE, TB, 0, stream>>>(ei, E, N, counts);
    k_scan<<<1, 1024, 0, stream>>>(counts, N, rowptr, cursor);
    k_scatter<<<gE, TB, 0, stream>>>(ei, E, N, cursor, col);

    // layer 1
    k_gemm1<<<(N + 7) / 8, 128, 0, stream>>>(x, W1, h1, N);
    k_att1<<<N, 128, 0, stream>>>(h1, a1sw, a1dw, a1s, a1d, N);
    k_aggr1<<<(N + 3) / 4, 256, 0, stream>>>(rowptr, col, h1, a1s, a1d, b1, g1, N);

    // layer 2
    k_gemm2<<<N, 64, 0, stream>>>(g1, W2, a2sw, a2dw, h2, a2s, a2d, N);
    k_aggr2<<<(N + 3) / 4, 256, 0, stream>>>(rowptr, col, h2, a2s, a2d, b2, zout, N);

    // decoder (split: first layer is linear over the concat)
    k_uv<<<(N + 3) / 4, 256, 0, stream>>>(zout, Wd1, bd1, uu, vv, N);
    k_dec2<<<(E + 31) / 32, TB, 0, stream>>>(ei, E, uu, vv, Wd2, bd2, pred);
}

// Round 5
// 597.703 us; speedup vs baseline: 9.7901x; 1.0770x over previous
//
#include <hip/hip_runtime.h>
#include <hip/hip_bf16.h>
#include <math.h>

#define NEG_ATT 0.2f
#define NEG_ACT 0.01f
#define NEG_BIG -1e30f
#define NRANGE 8   // dst-space ranges, mapped to XCDs via blockIdx%8

// ============================ CSR build ============================
__global__ void k_zero(int* __restrict__ counts, int N) {
    int i = blockIdx.x * blockDim.x + threadIdx.x;
    if (i < N) counts[i] = 0;
}

__global__ void k_count(const int* __restrict__ ei, int E, int N, int* __restrict__ counts) {
    int e = blockIdx.x * blockDim.x + threadIdx.x;
    if (e >= E + N) return;
    int d = (e < E) ? ei[E + e] : e - E;
    atomicAdd(&counts[d], 1);
}

// single-block 1024-thread exclusive scan over counts[0..N) -> rowptr[0..N], cursor copy
__global__ void k_scan(const int* __restrict__ counts, int N,
                       int* __restrict__ rowptr, int* __restrict__ cursor) {
    __shared__ int ps[1024];
    const int t = threadIdx.x;
    const int C = (N + 1023) >> 10;
    const int lo = t * C, hi = min(lo + C, N);
    int sum = 0;
    for (int i = lo; i < hi; ++i) sum += counts[i];
    ps[t] = sum;
    __syncthreads();
    for (int off = 1; off < 1024; off <<= 1) {
        int v = (t >= off) ? ps[t - off] : 0;
        __syncthreads();
        ps[t] += v;
        __syncthreads();
    }
    int run = ps[t] - sum;   // exclusive prefix
    for (int i = lo; i < hi; ++i) {
        rowptr[i] = run; cursor[i] = run;
        run += counts[i];
    }
    if (t == 1023) rowptr[N] = ps[1023];
}

// XCD-range-partitioned scatter: range r = blockIdx&7 handles dst in [r*N/8,(r+1)*N/8).
// Each XCD's L2 then owns a contiguous col[] window -> full-line writebacks.
__global__ void k_scatter(const int* __restrict__ ei, int E, int N,
                          int* __restrict__ cursor, int* __restrict__ col) {
    const int r = blockIdx.x & (NRANGE - 1);
    const int e = (blockIdx.x >> 3) * blockDim.x + threadIdx.x;
    if (e >= E + N) return;
    const int dlo = (int)(((long)r * N) / NRANGE);
    const int dhi = (int)(((long)(r + 1) * N) / NRANGE);
    int d = (e < E) ? ei[E + e] : e - E;
    if (d < dlo || d >= dhi) return;
    int s = (e < E) ? ei[e] : d;
    int pos = atomicAdd(&cursor[d], 1);
    col[pos] = s;
}

// ============================ GEMM1: h1 = x @ W1  [N,128]x[128,128] ============================
__global__ void k_gemm1(const float* __restrict__ x, const float* __restrict__ W1,
                        float* __restrict__ h1, int N) {
    __shared__ float xs[8][128];
    const int j = threadIdx.x;
    const int row0 = blockIdx.x * 8;
    #pragma unroll
    for (int r = 0; r < 8; ++r) {
        int n = row0 + r;
        xs[r][j] = (n < N) ? x[(long)n * 128 + j] : 0.f;
    }
    __syncthreads();
    float acc[8];
    #pragma unroll
    for (int r = 0; r < 8; ++r) acc[r] = 0.f;
    for (int k = 0; k < 128; ++k) {
        float w = W1[k * 128 + j];
        #pragma unroll
        for (int r = 0; r < 8; ++r) acc[r] = fmaf(xs[r][k], w, acc[r]);
    }
    #pragma unroll
    for (int r = 0; r < 8; ++r) {
        int n = row0 + r;
        if (n < N) h1[(long)n * 128 + j] = acc[r];
    }
}

// ============================ attention coeffs layer 1 ============================
__global__ void k_att1(const float* __restrict__ h1, const float* __restrict__ as,
                       const float* __restrict__ ad,
                       float* __restrict__ a1s, float* __restrict__ a1d, int N) {
    const int n = blockIdx.x, j = threadIdx.x;   // 128 threads
    float h = h1[(long)n * 128 + j];
    float vs = h * as[j], vd = h * ad[j];
    #pragma unroll
    for (int m = 16; m >= 1; m >>= 1) {
        vs += __shfl_xor(vs, m, 32);
        vd += __shfl_xor(vd, m, 32);
    }
    if ((j & 31) == 0) { a1s[n * 4 + (j >> 5)] = vs; a1d[n * 4 + (j >> 5)] = vd; }
}

// ============================ layer-1 fused softmax+aggregate, one wave per dst ============================
__global__ void k_aggr1(const int* __restrict__ rowptr, const int* __restrict__ col,
                        const float* __restrict__ h1, const float* __restrict__ a1s,
                        const float* __restrict__ a1d, const float* __restrict__ b1,
                        float* __restrict__ g1, int N) {
    __shared__ float als[4][64][4];
    __shared__ int   scol[4][64];
    const int w = threadIdx.x >> 6;
    const int lane = threadIdx.x & 63;
    const int d = blockIdx.x * 4 + w;
    if (d >= N) return;
    const int lo = rowptr[d], hi = rowptr[d + 1];
    const float4 ad4 = *(const float4*)&a1d[d * 4];

    // ---- phase 1: online softmax stats per head (strided over edges) ----
    float mx0 = NEG_BIG, mx1 = NEG_BIG, mx2 = NEG_BIG, mx3 = NEG_BIG;
    float sm0 = 0.f, sm1 = 0.f, sm2 = 0.f, sm3 = 0.f;
    for (int j = lo + lane; j < hi; j += 64) {
        int s = col[j];
        float4 as4 = *(const float4*)&a1s[s * 4];
        float a0 = as4.x + ad4.x, a1 = as4.y + ad4.y, a2 = as4.z + ad4.z, a3 = as4.w + ad4.w;
        a0 = a0 > 0.f ? a0 : NEG_ATT * a0;
        a1 = a1 > 0.f ? a1 : NEG_ATT * a1;
        a2 = a2 > 0.f ? a2 : NEG_ATT * a2;
        a3 = a3 > 0.f ? a3 : NEG_ATT * a3;
        float m;
        m = fmaxf(mx0, a0); sm0 = sm0 * __expf(mx0 - m) + __expf(a0 - m); mx0 = m;
        m = fmaxf(mx1, a1); sm1 = sm1 * __expf(mx1 - m) + __expf(a1 - m); mx1 = m;
        m = fmaxf(mx2, a2); sm2 = sm2 * __expf(mx2 - m) + __expf(a2 - m); mx2 = m;
        m = fmaxf(mx3, a3); sm3 = sm3 * __expf(mx3 - m) + __expf(a3 - m); mx3 = m;
    }
    #pragma unroll
    for (int off = 32; off >= 1; off >>= 1) {
        float mo, so, m;
        mo = __shfl_xor(mx0, off); so = __shfl_xor(sm0, off);
        m = fmaxf(mx0, mo); sm0 = sm0 * __expf(mx0 - m) + so * __expf(mo - m); mx0 = m;
        mo = __shfl_xor(mx1, off); so = __shfl_xor(sm1, off);
        m = fmaxf(mx1, mo); sm1 = sm1 * __expf(mx1 - m) + so * __expf(mo - m); mx1 = m;
        mo = __shfl_xor(mx2, off); so = __shfl_xor(sm2, off);
        m = fmaxf(mx2, mo); sm2 = sm2 * __expf(mx2 - m) + so * __expf(mo - m); mx2 = m;
        mo = __shfl_xor(mx3, off); so = __shfl_xor(sm3, off);
        m = fmaxf(mx3, mo); sm3 = sm3 * __expf(mx3 - m) + so * __expf(mo - m); mx3 = m;
    }
    const float inv0 = 1.f / (sm0 + 1e-16f), inv1 = 1.f / (sm1 + 1e-16f);
    const float inv2 = 1.f / (sm2 + 1e-16f), inv3 = 1.f / (sm3 + 1e-16f);

    // ---- phase 2: chunked alpha precompute + pure gather/FMA ----
    const int h0 = lane >> 5;
    float acc0 = 0.f, acc1 = 0.f;
    for (int base = lo; base < hi; base += 64) {
        const int cnt = min(64, hi - base);
        if (lane < cnt) {
            int s = col[base + lane];
            float4 as4 = *(const float4*)&a1s[s * 4];
            float a0 = as4.x + ad4.x, a1 = as4.y + ad4.y, a2 = as4.z + ad4.z, a3 = as4.w + ad4.w;
            a0 = a0 > 0.f ? a0 : NEG_ATT * a0;
            a1 = a1 > 0.f ? a1 : NEG_ATT * a1;
            a2 = a2 > 0.f ? a2 : NEG_ATT * a2;
            a3 = a3 > 0.f ? a3 : NEG_ATT * a3;
            float4 al;
            al.x = __expf(a0 - mx0) * inv0;
            al.y = __expf(a1 - mx1) * inv1;
            al.z = __expf(a2 - mx2) * inv2;
            al.w = __expf(a3 - mx3) * inv3;
            *(float4*)&als[w][lane][0] = al;
            scol[w][lane] = s;
        }
        __builtin_amdgcn_wave_barrier();
        for (int t = 0; t < cnt; ++t) {
            int s = scol[w][t];
            float alA = als[w][t][h0];
            float alB = als[w][t][2 + h0];
            acc0 = fmaf(h1[(long)s * 128 + lane], alA, acc0);
            acc1 = fmaf(h1[(long)s * 128 + 64 + lane], alB, acc1);
        }
        __builtin_amdgcn_wave_barrier();
    }
    g1[(long)d * 128 + lane]      = acc0 + b1[lane];
    g1[(long)d * 128 + 64 + lane] = acc1 + b1[64 + lane];
}

// ============================ GEMM2 fused: h2 = leaky(g1) @ W2, + a2s/a2d ============================
__global__ void k_gemm2(const float* __restrict__ g1, const float* __restrict__ W2,
                        const float* __restrict__ a2srcv, const float* __restrict__ a2dstv,
                        float* __restrict__ h2, float* __restrict__ a2s, float* __restrict__ a2d,
                        int N) {
    __shared__ float xs[128];
    const int n = blockIdx.x, j = threadIdx.x;   // 64 threads
    for (int t = j; t < 128; t += 64) {
        float v = g1[(long)n * 128 + t];
        xs[t] = v > 0.f ? v : NEG_ACT * v;
    }
    __syncthreads();
    float acc = 0.f;
    for (int k = 0; k < 128; ++k) acc = fmaf(xs[k], W2[k * 64 + j], acc);
    h2[(long)n * 64 + j] = acc;
    float vs = acc * a2srcv[j], vd = acc * a2dstv[j];
    #pragma unroll
    for (int m = 32; m >= 1; m >>= 1) {
        vs += __shfl_xor(vs, m);
        vd += __shfl_xor(vd, m);
    }
    if (j == 0) { a2s[n] = vs; a2d[n] = vd; }
}

// ============================ layer-2 fused softmax+aggregate, one wave per dst ============================
__global__ void k_aggr2(const int* __restrict__ rowptr, const int* __restrict__ col,
                        const float* __restrict__ h2, const float* __restrict__ a2s,
                        const float* __restrict__ a2d, const float* __restrict__ b2,
                        float* __restrict__ zout, int N) {
    __shared__ float als[4][64];
    __shared__ int   scol[4][64];
    const int w = threadIdx.x >> 6;
    const int lane = threadIdx.x & 63;
    const int d = blockIdx.x * 4 + w;
    if (d >= N) return;
    const int lo = rowptr[d], hi = rowptr[d + 1];
    const float ad = a2d[d];

    float mx = NEG_BIG, sm = 0.f;
    for (int j = lo + lane; j < hi; j += 64) {
        int s = col[j];
        float a = a2s[s] + ad;
        a = a > 0.f ? a : NEG_ATT * a;
        float m = fmaxf(mx, a);
        sm = sm * __expf(mx - m) + __expf(a - m);
        mx = m;
    }
    #pragma unroll
    for (int off = 32; off >= 1; off >>= 1) {
        float mo = __shfl_xor(mx, off), so = __shfl_xor(sm, off);
        float m = fmaxf(mx, mo);
        sm = sm * __expf(mx - m) + so * __expf(mo - m);
        mx = m;
    }
    const float inv = 1.f / (sm + 1e-16f);

    float acc = 0.f;
    for (int base = lo; base < hi; base += 64) {
        const int cnt = min(64, hi - base);
        if (lane < cnt) {
            int s = col[base + lane];
            float a = a2s[s] + ad;
            a = a > 0.f ? a : NEG_ATT * a;
            als[w][lane] = __expf(a - mx) * inv;
            scol[w][lane] = s;
        }
        __builtin_amdgcn_wave_barrier();
        for (int t = 0; t < cnt; ++t) {
            int s = scol[w][t];
            acc = fmaf(h2[(long)s * 64 + lane], als[w][t], acc);
        }
        __builtin_amdgcn_wave_barrier();
    }
    zout[(long)d * 64 + lane] = acc + b2[lane];
}

// ============================ decoder node-level precompute ============================
__global__ void k_uv(const float* __restrict__ z, const float* __restrict__ Wd1,
                     const float* __restrict__ bd1,
                     float* __restrict__ u, float* __restrict__ v, int N) {
    __shared__ float zs[4][64];
    const int w = threadIdx.x >> 6;              // node slot 0..3
    const int lane = threadIdx.x & 63;
    const int n = blockIdx.x * 4 + w;
    if (n < N) zs[w][lane] = z[(long)n * 64 + lane];
    __syncthreads();
    if (n >= N) return;
    const int jj = lane & 31;
    const int base = (lane < 32) ? 0 : 64 * 32;  // top half -> u, bottom -> v
    float acc = (lane < 32) ? bd1[jj] : 0.f;
    #pragma unroll
    for (int k = 0; k < 64; ++k)
        acc = fmaf(zs[w][k], Wd1[base + k * 32 + jj], acc);
    if (lane < 32) u[(long)n * 32 + jj] = acc;
    else           v[(long)n * 32 + jj] = acc;
}

// ============================ decoder per-edge: relu(u[s]+v[d]) . Wd2 + bd2 ============================
__global__ void k_dec2(const int* __restrict__ ei, int E,
                       const float* __restrict__ u, const float* __restrict__ v,
                       const float* __restrict__ Wd2, const float* __restrict__ bd2,
                       float* __restrict__ pred) {
    const int g = threadIdx.x >> 3;      // edge slot 0..31
    const int l = threadIdx.x & 7;       // lane in group
    long e = (long)blockIdx.x * 32 + g;
    if (e >= E) return;
    int s = ei[e], d = ei[E + e];
    float4 a = *(const float4*)&u[(long)s * 32 + l * 4];
    float4 b = *(const float4*)&v[(long)d * 32 + l * 4];
    float4 wv = *(const float4*)&Wd2[l * 4];
    float h0 = fmaxf(a.x + b.x, 0.f);
    float h1 = fmaxf(a.y + b.y, 0.f);
    float h2 = fmaxf(a.z + b.z, 0.f);
    float h3 = fmaxf(a.w + b.w, 0.f);
    float p = h0 * wv.x;
    p = fmaf(h1, wv.y, p);
    p = fmaf(h2, wv.z, p);
    p = fmaf(h3, wv.w, p);
    p += __shfl_xor(p, 1, 8);
    p += __shfl_xor(p, 2, 8);
    p += __shfl_xor(p, 4, 8);
    if (l == 0) pred[e] = p + bd2[0];
}

// ============================ launch ============================
extern "C" void kernel_launch(void* const* d_in, const int* in_sizes, int n_in,
                              void* d_out, int out_size, void* d_ws, size_t ws_size,
                              hipStream_t stream) {
    const float* x    = (const float*)d_in[0];
    const int*   ei   = (const int*)d_in[1];
    const float* W1   = (const float*)d_in[2];
    const float* a1sw = (const float*)d_in[3];
    const float* a1dw = (const float*)d_in[4];
    const float* b1   = (const float*)d_in[5];
    const float* W2   = (const float*)d_in[6];
    const float* a2sw = (const float*)d_in[7];
    const float* a2dw = (const float*)d_in[8];
    const float* b2   = (const float*)d_in[9];
    const float* Wd1  = (const float*)d_in[10];
    const float* bd1  = (const float*)d_in[11];
    const float* Wd2  = (const float*)d_in[12];
    const float* bd2  = (const float*)d_in[13];

    const int N = in_sizes[0] / 128;        // 50000
    const int E = in_sizes[1] / 2;          // 1600000
    const int E2 = E + N;

    float* pred = (float*)d_out;            // [E]
    float* zout = (float*)d_out + E;        // [N,64]

    // workspace layout
    float* W = (float*)d_ws;
    size_t o = 0;
    float* h1  = W + o; o += (size_t)N * 128;
    float* g1  = W + o; o += (size_t)N * 128;
    float* h2  = W + o; o += (size_t)N * 64;
    float* uu  = W + o; o += (size_t)N * 32;
    float* vv  = W + o; o += (size_t)N * 32;
    float* a1s = W + o; o += (size_t)N * 4;
    float* a1d = W + o; o += (size_t)N * 4;
    float* a2s = W + o; o += (size_t)N;
    float* a2d = W + o; o += (size_t)N;
    int* counts = (int*)(W + o); o += (size_t)N;
    int* rowptr = (int*)(W + o); o += (size_t)N + 1;
    int* cursor = (int*)(W + o); o += (size_t)N;
    int* col    = (int*)(W + o); o += (size_t)E2;
    if (ws_size < o * sizeof(float)) return;

    const int TB = 256;
    const int gE = (E2 + TB - 1) / TB;

    // CSR build
    k_zero<<<(N + TB - 1) / TB, TB, 0, stream>>>(counts, N);
    k_count<<<gE, TB, 0, stream>>>(ei, E, N, counts);
    k_scan<<<1, 1024, 0, stream>>>(counts, N, rowptr, cursor);
    k_scatter<<<gE * NRANGE, TB, 0, stream>>>(ei, E, N, cursor, col);

    // layer 1
    k_gemm1<<<(N + 7) / 8, 128, 0, stream>>>(x, W1, h1, N);
    k_att1<<<N, 128, 0, stream>>>(h1, a1sw, a1dw, a1s, a1d, N);
    k_aggr1<<<(N + 3) / 4, 256, 0, stream>>>(rowptr, col, h1, a1s, a1d, b1, g1, N);

    // layer 2
    k_gemm2<<<N, 64, 0, stream>>>(g1, W2, a2sw, a2dw, h2, a2s, a2d, N);
    k_aggr2<<<(N + 3) / 4, 256, 0, stream>>>(rowptr, col, h2, a2s, a2d, b2, zout, N);

    // decoder (split: first layer is linear over the concat)
    k_uv<<<(N + 3) / 4, 256, 0, stream>>>(zout, Wd1, bd1, uu, vv, N);
    k_dec2<<<(E + 31) / 32, TB, 0, stream>>>(ei, E, uu, vv, Wd2, bd2, pred);
}

// Round 6
// 556.667 us; speedup vs baseline: 10.5118x; 1.0737x over previous
//
#include <hip/hip_runtime.h>
#include <hip/hip_bf16.h>
#include <math.h>

#define NEG_ATT 0.2f
#define NEG_ACT 0.01f
#define NEG_BIG -1e30f
#define NRANGE 8   // dst-space ranges, mapped to XCDs via blockIdx%8

typedef __hip_bfloat16  bf16;
typedef __hip_bfloat162 bf16x2;

// ============================ CSR build ============================
__global__ void k_zero(int* __restrict__ counts, int N) {
    int i = blockIdx.x * blockDim.x + threadIdx.x;
    if (i < N) counts[i] = 0;
}

// XCD-range-partitioned count: range r handles dst in [r*N/8,(r+1)*N/8) so each
// XCD's L2 owns its counts slice (no cross-XCD line ping-pong).
__global__ void k_count(const int* __restrict__ ei, int E, int N, int* __restrict__ counts) {
    const int r = blockIdx.x & (NRANGE - 1);
    const int e = (blockIdx.x >> 3) * blockDim.x + threadIdx.x;
    if (e >= E + N) return;
    const int dlo = (int)(((long)r * N) / NRANGE);
    const int dhi = (int)(((long)(r + 1) * N) / NRANGE);
    int d = (e < E) ? ei[E + e] : e - E;
    if (d < dlo || d >= dhi) return;
    atomicAdd(&counts[d], 1);
}

// single-block 1024-thread exclusive scan over counts[0..N) -> rowptr[0..N], cursor copy
__global__ void k_scan(const int* __restrict__ counts, int N,
                       int* __restrict__ rowptr, int* __restrict__ cursor) {
    __shared__ int ps[1024];
    const int t = threadIdx.x;
    const int C = (N + 1023) >> 10;
    const int lo = t * C, hi = min(lo + C, N);
    int sum = 0;
    for (int i = lo; i < hi; ++i) sum += counts[i];
    ps[t] = sum;
    __syncthreads();
    for (int off = 1; off < 1024; off <<= 1) {
        int v = (t >= off) ? ps[t - off] : 0;
        __syncthreads();
        ps[t] += v;
        __syncthreads();
    }
    int run = ps[t] - sum;   // exclusive prefix
    for (int i = lo; i < hi; ++i) {
        rowptr[i] = run; cursor[i] = run;
        run += counts[i];
    }
    if (t == 1023) rowptr[N] = ps[1023];
}

// XCD-range-partitioned scatter (full-line writebacks per XCD-owned col window)
__global__ void k_scatter(const int* __restrict__ ei, int E, int N,
                          int* __restrict__ cursor, int* __restrict__ col) {
    const int r = blockIdx.x & (NRANGE - 1);
    const int e = (blockIdx.x >> 3) * blockDim.x + threadIdx.x;
    if (e >= E + N) return;
    const int dlo = (int)(((long)r * N) / NRANGE);
    const int dhi = (int)(((long)(r + 1) * N) / NRANGE);
    int d = (e < E) ? ei[E + e] : e - E;
    if (d < dlo || d >= dhi) return;
    int s = (e < E) ? ei[e] : d;
    int pos = atomicAdd(&cursor[d], 1);
    col[pos] = s;
}

// ============================ GEMM1: h1 = x @ W1  (fp32 out + bf16 gather copy) ============================
__global__ void k_gemm1(const float* __restrict__ x, const float* __restrict__ W1,
                        float* __restrict__ h1, bf16* __restrict__ h1b, int N) {
    __shared__ float xs[8][128];
    const int j = threadIdx.x;
    const int row0 = blockIdx.x * 8;
    #pragma unroll
    for (int r = 0; r < 8; ++r) {
        int n = row0 + r;
        xs[r][j] = (n < N) ? x[(long)n * 128 + j] : 0.f;
    }
    __syncthreads();
    float acc[8];
    #pragma unroll
    for (int r = 0; r < 8; ++r) acc[r] = 0.f;
    for (int k = 0; k < 128; ++k) {
        float w = W1[k * 128 + j];
        #pragma unroll
        for (int r = 0; r < 8; ++r) acc[r] = fmaf(xs[r][k], w, acc[r]);
    }
    #pragma unroll
    for (int r = 0; r < 8; ++r) {
        int n = row0 + r;
        if (n < N) {
            h1[(long)n * 128 + j]  = acc[r];
            h1b[(long)n * 128 + j] = __float2bfloat16(acc[r]);
        }
    }
}

// ============================ attention coeffs layer 1 (from fp32 h1) ============================
__global__ void k_att1(const float* __restrict__ h1, const float* __restrict__ as,
                       const float* __restrict__ ad,
                       float* __restrict__ a1s, float* __restrict__ a1d, int N) {
    const int n = blockIdx.x, j = threadIdx.x;   // 128 threads
    float h = h1[(long)n * 128 + j];
    float vs = h * as[j], vd = h * ad[j];
    #pragma unroll
    for (int m = 16; m >= 1; m >>= 1) {
        vs += __shfl_xor(vs, m, 32);
        vd += __shfl_xor(vd, m, 32);
    }
    if ((j & 31) == 0) { a1s[n * 4 + (j >> 5)] = vs; a1d[n * 4 + (j >> 5)] = vd; }
}

// ============================ layer-1 fused softmax+aggregate ============================
// lane owns channel pair {2*lane, 2*lane+1} (same head); gather is one bf16x2 dword per edge.
__global__ void k_aggr1(const int* __restrict__ rowptr, const int* __restrict__ col,
                        const bf16x2* __restrict__ h1r, const float* __restrict__ a1s,
                        const float* __restrict__ a1d, const float* __restrict__ b1,
                        float* __restrict__ g1, int N) {
    __shared__ float als[4][64][4];
    __shared__ int   scol[4][64];
    const int w = threadIdx.x >> 6;
    const int lane = threadIdx.x & 63;
    const int d = blockIdx.x * 4 + w;
    if (d >= N) return;
    const int lo = rowptr[d], hi = rowptr[d + 1];
    const float4 ad4 = *(const float4*)&a1d[d * 4];

    // ---- phase 1: online softmax stats per head ----
    float mx0 = NEG_BIG, mx1 = NEG_BIG, mx2 = NEG_BIG, mx3 = NEG_BIG;
    float sm0 = 0.f, sm1 = 0.f, sm2 = 0.f, sm3 = 0.f;
    for (int j = lo + lane; j < hi; j += 64) {
        int s = col[j];
        float4 as4 = *(const float4*)&a1s[s * 4];
        float a0 = as4.x + ad4.x, a1 = as4.y + ad4.y, a2 = as4.z + ad4.z, a3 = as4.w + ad4.w;
        a0 = a0 > 0.f ? a0 : NEG_ATT * a0;
        a1 = a1 > 0.f ? a1 : NEG_ATT * a1;
        a2 = a2 > 0.f ? a2 : NEG_ATT * a2;
        a3 = a3 > 0.f ? a3 : NEG_ATT * a3;
        float m;
        m = fmaxf(mx0, a0); sm0 = sm0 * __expf(mx0 - m) + __expf(a0 - m); mx0 = m;
        m = fmaxf(mx1, a1); sm1 = sm1 * __expf(mx1 - m) + __expf(a1 - m); mx1 = m;
        m = fmaxf(mx2, a2); sm2 = sm2 * __expf(mx2 - m) + __expf(a2 - m); mx2 = m;
        m = fmaxf(mx3, a3); sm3 = sm3 * __expf(mx3 - m) + __expf(a3 - m); mx3 = m;
    }
    #pragma unroll
    for (int off = 32; off >= 1; off >>= 1) {
        float mo, so, m;
        mo = __shfl_xor(mx0, off); so = __shfl_xor(sm0, off);
        m = fmaxf(mx0, mo); sm0 = sm0 * __expf(mx0 - m) + so * __expf(mo - m); mx0 = m;
        mo = __shfl_xor(mx1, off); so = __shfl_xor(sm1, off);
        m = fmaxf(mx1, mo); sm1 = sm1 * __expf(mx1 - m) + so * __expf(mo - m); mx1 = m;
        mo = __shfl_xor(mx2, off); so = __shfl_xor(sm2, off);
        m = fmaxf(mx2, mo); sm2 = sm2 * __expf(mx2 - m) + so * __expf(mo - m); mx2 = m;
        mo = __shfl_xor(mx3, off); so = __shfl_xor(sm3, off);
        m = fmaxf(mx3, mo); sm3 = sm3 * __expf(mx3 - m) + so * __expf(mo - m); mx3 = m;
    }
    const float inv0 = 1.f / (sm0 + 1e-16f), inv1 = 1.f / (sm1 + 1e-16f);
    const float inv2 = 1.f / (sm2 + 1e-16f), inv3 = 1.f / (sm3 + 1e-16f);

    // ---- phase 2: chunked alpha precompute + bf16x2 gather ----
    const int hh = lane >> 4;                    // head of channels {2l,2l+1}
    float acc0 = 0.f, acc1 = 0.f;
    for (int base = lo; base < hi; base += 64) {
        const int cnt = min(64, hi - base);
        if (lane < cnt) {
            int s = col[base + lane];
            float4 as4 = *(const float4*)&a1s[s * 4];
            float a0 = as4.x + ad4.x, a1 = as4.y + ad4.y, a2 = as4.z + ad4.z, a3 = as4.w + ad4.w;
            a0 = a0 > 0.f ? a0 : NEG_ATT * a0;
            a1 = a1 > 0.f ? a1 : NEG_ATT * a1;
            a2 = a2 > 0.f ? a2 : NEG_ATT * a2;
            a3 = a3 > 0.f ? a3 : NEG_ATT * a3;
            float4 al;
            al.x = __expf(a0 - mx0) * inv0;
            al.y = __expf(a1 - mx1) * inv1;
            al.z = __expf(a2 - mx2) * inv2;
            al.w = __expf(a3 - mx3) * inv3;
            *(float4*)&als[w][lane][0] = al;
            scol[w][lane] = s;
        }
        __builtin_amdgcn_wave_barrier();
        for (int t = 0; t < cnt; ++t) {
            int s = scol[w][t];
            float al = als[w][t][hh];
            bf16x2 v = h1r[(long)s * 64 + lane];
            acc0 = fmaf(__bfloat162float(v.x), al, acc0);
            acc1 = fmaf(__bfloat162float(v.y), al, acc1);
        }
        __builtin_amdgcn_wave_barrier();
    }
    float2 outv;
    outv.x = acc0 + b1[2 * lane];
    outv.y = acc1 + b1[2 * lane + 1];
    *(float2*)&g1[(long)d * 128 + 2 * lane] = outv;
}

// ============================ GEMM2 fused: h2b = bf16(leaky(g1) @ W2), + a2s/a2d ============================
__global__ void k_gemm2(const float* __restrict__ g1, const float* __restrict__ W2,
                        const float* __restrict__ a2srcv, const float* __restrict__ a2dstv,
                        bf16* __restrict__ h2b, float* __restrict__ a2s, float* __restrict__ a2d,
                        int N) {
    __shared__ float xs[128];
    const int n = blockIdx.x, j = threadIdx.x;   // 64 threads
    for (int t = j; t < 128; t += 64) {
        float v = g1[(long)n * 128 + t];
        xs[t] = v > 0.f ? v : NEG_ACT * v;
    }
    __syncthreads();
    float acc = 0.f;
    for (int k = 0; k < 128; ++k) acc = fmaf(xs[k], W2[k * 64 + j], acc);
    h2b[(long)n * 64 + j] = __float2bfloat16(acc);
    float vs = acc * a2srcv[j], vd = acc * a2dstv[j];
    #pragma unroll
    for (int m = 32; m >= 1; m >>= 1) {
        vs += __shfl_xor(vs, m);
        vd += __shfl_xor(vd, m);
    }
    if (j == 0) { a2s[n] = vs; a2d[n] = vd; }
}

// ============================ layer-2 fused softmax+aggregate ============================
// 2 edges/iter: half-wave (32 lanes) per edge, lane owns channel pair {2c,2c+1}; shfl(32) combine.
__global__ void k_aggr2(const int* __restrict__ rowptr, const int* __restrict__ col,
                        const bf16x2* __restrict__ h2r, const float* __restrict__ a2s,
                        const float* __restrict__ a2d, const float* __restrict__ b2,
                        float* __restrict__ zout, int N) {
    __shared__ float als[4][64];
    __shared__ int   scol[4][64];
    const int w = threadIdx.x >> 6;
    const int lane = threadIdx.x & 63;
    const int half = lane >> 5, c = lane & 31;
    const int d = blockIdx.x * 4 + w;
    if (d >= N) return;
    const int lo = rowptr[d], hi = rowptr[d + 1];
    const float ad = a2d[d];

    float mx = NEG_BIG, sm = 0.f;
    for (int j = lo + lane; j < hi; j += 64) {
        int s = col[j];
        float a = a2s[s] + ad;
        a = a > 0.f ? a : NEG_ATT * a;
        float m = fmaxf(mx, a);
        sm = sm * __expf(mx - m) + __expf(a - m);
        mx = m;
    }
    #pragma unroll
    for (int off = 32; off >= 1; off >>= 1) {
        float mo = __shfl_xor(mx, off), so = __shfl_xor(sm, off);
        float m = fmaxf(mx, mo);
        sm = sm * __expf(mx - m) + so * __expf(mo - m);
        mx = m;
    }
    const float inv = 1.f / (sm + 1e-16f);

    float acc0 = 0.f, acc1 = 0.f;
    for (int base = lo; base < hi; base += 64) {
        const int cnt = min(64, hi - base);
        if (lane < cnt) {
            int s = col[base + lane];
            float a = a2s[s] + ad;
            a = a > 0.f ? a : NEG_ATT * a;
            als[w][lane] = __expf(a - mx) * inv;
            scol[w][lane] = s;
        }
        __builtin_amdgcn_wave_barrier();
        for (int t = 0; t < cnt; t += 2) {
            int tt = t + half;
            if (tt < cnt) {
                int s = scol[w][tt];
                float al = als[w][tt];
                bf16x2 v = h2r[(long)s * 32 + c];
                acc0 = fmaf(__bfloat162float(v.x), al, acc0);
                acc1 = fmaf(__bfloat162float(v.y), al, acc1);
            }
        }
        __builtin_amdgcn_wave_barrier();
    }
    acc0 += __shfl_xor(acc0, 32);
    acc1 += __shfl_xor(acc1, 32);
    if (half == 0) {
        float2 outv;
        outv.x = acc0 + b2[2 * c];
        outv.y = acc1 + b2[2 * c + 1];
        *(float2*)&zout[(long)d * 64 + 2 * c] = outv;
    }
}

// ============================ decoder node-level precompute (bf16 out) ============================
__global__ void k_uv(const float* __restrict__ z, const float* __restrict__ Wd1,
                     const float* __restrict__ bd1,
                     bf16* __restrict__ u, bf16* __restrict__ v, int N) {
    __shared__ float zs[4][64];
    const int w = threadIdx.x >> 6;              // node slot 0..3
    const int lane = threadIdx.x & 63;
    const int n = blockIdx.x * 4 + w;
    if (n < N) zs[w][lane] = z[(long)n * 64 + lane];
    __syncthreads();
    if (n >= N) return;
    const int jj = lane & 31;
    const int base = (lane < 32) ? 0 : 64 * 32;  // top half -> u, bottom -> v
    float acc = (lane < 32) ? bd1[jj] : 0.f;
    #pragma unroll
    for (int k = 0; k < 64; ++k)
        acc = fmaf(zs[w][k], Wd1[base + k * 32 + jj], acc);
    if (lane < 32) u[(long)n * 32 + jj] = __float2bfloat16(acc);
    else           v[(long)n * 32 + jj] = __float2bfloat16(acc);
}

// ============================ decoder per-edge: relu(u[s]+v[d]) . Wd2 + bd2 ============================
// 8 lanes/edge; each lane loads 4 channels as bf16x4 (8B) -> 64B coalesced rows.
__global__ void k_dec2(const int* __restrict__ ei, int E,
                       const bf16* __restrict__ u, const bf16* __restrict__ v,
                       const float* __restrict__ Wd2, const float* __restrict__ bd2,
                       float* __restrict__ pred) {
    const int g = threadIdx.x >> 3;      // edge slot 0..31
    const int l = threadIdx.x & 7;       // lane in group
    long e = (long)blockIdx.x * 32 + g;
    if (e >= E) return;
    int s = ei[e], d = ei[E + e];
    uint2 ua = *(const uint2*)(u + (long)s * 32 + l * 4);
    uint2 vb = *(const uint2*)(v + (long)d * 32 + l * 4);
    bf16x2 ua0 = *(bf16x2*)&ua.x, ua1 = *(bf16x2*)&ua.y;
    bf16x2 vb0 = *(bf16x2*)&vb.x, vb1 = *(bf16x2*)&vb.y;
    float4 wv = *(const float4*)&Wd2[l * 4];
    float h0 = fmaxf(__bfloat162float(ua0.x) + __bfloat162float(vb0.x), 0.f);
    float h1 = fmaxf(__bfloat162float(ua0.y) + __bfloat162float(vb0.y), 0.f);
    float h2 = fmaxf(__bfloat162float(ua1.x) + __bfloat162float(vb1.x), 0.f);
    float h3 = fmaxf(__bfloat162float(ua1.y) + __bfloat162float(vb1.y), 0.f);
    float p = h0 * wv.x;
    p = fmaf(h1, wv.y, p);
    p = fmaf(h2, wv.z, p);
    p = fmaf(h3, wv.w, p);
    p += __shfl_xor(p, 1, 8);
    p += __shfl_xor(p, 2, 8);
    p += __shfl_xor(p, 4, 8);
    if (l == 0) pred[e] = p + bd2[0];
}

// ============================ launch ============================
extern "C" void kernel_launch(void* const* d_in, const int* in_sizes, int n_in,
                              void* d_out, int out_size, void* d_ws, size_t ws_size,
                              hipStream_t stream) {
    const float* x    = (const float*)d_in[0];
    const int*   ei   = (const int*)d_in[1];
    const float* W1   = (const float*)d_in[2];
    const float* a1sw = (const float*)d_in[3];
    const float* a1dw = (const float*)d_in[4];
    const float* b1   = (const float*)d_in[5];
    const float* W2   = (const float*)d_in[6];
    const float* a2sw = (const float*)d_in[7];
    const float* a2dw = (const float*)d_in[8];
    const float* b2   = (const float*)d_in[9];
    const float* Wd1  = (const float*)d_in[10];
    const float* bd1  = (const float*)d_in[11];
    const float* Wd2  = (const float*)d_in[12];
    const float* bd2  = (const float*)d_in[13];

    const int N = in_sizes[0] / 128;        // 50000
    const int E = in_sizes[1] / 2;          // 1600000
    const int E2 = E + N;

    float* pred = (float*)d_out;            // [E]
    float* zout = (float*)d_out + E;        // [N,64]

    // workspace layout (float-slot units)
    float* W = (float*)d_ws;
    size_t o = 0;
    float* h1  = W + o; o += (size_t)N * 128;
    float* g1  = W + o; o += (size_t)N * 128;
    bf16* h1b  = (bf16*)(W + o); o += (size_t)N * 64;   // N*128 bf16
    bf16* h2b  = (bf16*)(W + o); o += (size_t)N * 32;   // N*64 bf16
    bf16* ub   = (bf16*)(W + o); o += (size_t)N * 16;   // N*32 bf16
    bf16* vb   = (bf16*)(W + o); o += (size_t)N * 16;   // N*32 bf16
    float* a1s = W + o; o += (size_t)N * 4;
    float* a1d = W + o; o += (size_t)N * 4;
    float* a2s = W + o; o += (size_t)N;
    float* a2d = W + o; o += (size_t)N;
    int* counts = (int*)(W + o); o += (size_t)N;
    int* rowptr = (int*)(W + o); o += (size_t)N + 1;
    int* cursor = (int*)(W + o); o += (size_t)N;
    int* col    = (int*)(W + o); o += (size_t)E2;
    if (ws_size < o * sizeof(float)) return;

    const int TB = 256;
    const int gE = (E2 + TB - 1) / TB;

    // CSR build
    k_zero<<<(N + TB - 1) / TB, TB, 0, stream>>>(counts, N);
    k_count<<<gE * NRANGE, TB, 0, stream>>>(ei, E, N, counts);
    k_scan<<<1, 1024, 0, stream>>>(counts, N, rowptr, cursor);
    k_scatter<<<gE * NRANGE, TB, 0, stream>>>(ei, E, N, cursor, col);

    // layer 1
    k_gemm1<<<(N + 7) / 8, 128, 0, stream>>>(x, W1, h1, h1b, N);
    k_att1<<<N, 128, 0, stream>>>(h1, a1sw, a1dw, a1s, a1d, N);
    k_aggr1<<<(N + 3) / 4, 256, 0, stream>>>(rowptr, col, (const bf16x2*)h1b, a1s, a1d, b1, g1, N);

    // layer 2
    k_gemm2<<<N, 64, 0, stream>>>(g1, W2, a2sw, a2dw, h2b, a2s, a2d, N);
    k_aggr2<<<(N + 3) / 4, 256, 0, stream>>>(rowptr, col, (const bf16x2*)h2b, a2s, a2d, b2, zout, N);

    // decoder (split: first layer is linear over the concat)
    k_uv<<<(N + 3) / 4, 256, 0, stream>>>(zout, Wd1, bd1, ub, vb, N);
    k_dec2<<<(E + 31) / 32, TB, 0, stream>>>(ei, E, ub, vb, Wd2, bd2, pred);
}

// Round 7
// 456.859 us; speedup vs baseline: 12.8083x; 1.2185x over previous
//
#include <hip/hip_runtime.h>
#include <hip/hip_bf16.h>
#include <math.h>

#define NEG_ATT 0.2f
#define NEG_ACT 0.01f
#define NEG_BIG -1e30f
#define NRANGE 8   // dst-space ranges, mapped to XCDs via blockIdx%8

typedef __hip_bfloat16  bf16;
typedef __hip_bfloat162 bf16x2;

// ============================ CSR build ============================
__global__ void k_zero(int* __restrict__ counts, int N) {
    int i = blockIdx.x * blockDim.x + threadIdx.x;
    if (i < N) counts[i] = 0;
}

// XCD-range-partitioned count
__global__ void k_count(const int* __restrict__ ei, int E, int N, int* __restrict__ counts) {
    const int r = blockIdx.x & (NRANGE - 1);
    const int e = (blockIdx.x >> 3) * blockDim.x + threadIdx.x;
    if (e >= E + N) return;
    const int dlo = (int)(((long)r * N) / NRANGE);
    const int dhi = (int)(((long)(r + 1) * N) / NRANGE);
    int d = (e < E) ? ei[E + e] : e - E;
    if (d < dlo || d >= dhi) return;
    atomicAdd(&counts[d], 1);
}

// ---- hierarchical scan: phase 1, per-block (256-wide) sums ----
__global__ void k_scan1(const int* __restrict__ counts, int N, int* __restrict__ bsum) {
    const int i = blockIdx.x * 256 + threadIdx.x;
    int v = (i < N) ? counts[i] : 0;
    #pragma unroll
    for (int off = 32; off >= 1; off >>= 1) v += __shfl_xor(v, off);
    __shared__ int ws[4];
    if ((threadIdx.x & 63) == 0) ws[threadIdx.x >> 6] = v;
    __syncthreads();
    if (threadIdx.x == 0) bsum[blockIdx.x] = ws[0] + ws[1] + ws[2] + ws[3];
}

// ---- phase 2: single small block scans the block sums (NB<=256), writes rowptr[N] ----
__global__ void k_scan2(int* __restrict__ bsum, int NB, int* __restrict__ rowptrN) {
    __shared__ int ps[256];
    const int t = threadIdx.x;
    int v = (t < NB) ? bsum[t] : 0;
    ps[t] = v;
    __syncthreads();
    for (int off = 1; off < 256; off <<= 1) {
        int u = (t >= off) ? ps[t - off] : 0;
        __syncthreads();
        ps[t] += u;
        __syncthreads();
    }
    if (t < NB) bsum[t] = ps[t] - v;          // exclusive
    if (t == 255) *rowptrN = ps[255];         // total
}

// ---- phase 3: block-local exclusive scan + global offset ----
__global__ void k_scan3(const int* __restrict__ counts, int N, const int* __restrict__ bsum,
                        int* __restrict__ rowptr, int* __restrict__ cursor) {
    __shared__ int ps[256];
    const int t = threadIdx.x;
    const int i = blockIdx.x * 256 + t;
    int v = (i < N) ? counts[i] : 0;
    ps[t] = v;
    __syncthreads();
    for (int off = 1; off < 256; off <<= 1) {
        int u = (t >= off) ? ps[t - off] : 0;
        __syncthreads();
        ps[t] += u;
        __syncthreads();
    }
    if (i < N) {
        int ex = ps[t] - v + bsum[blockIdx.x];
        rowptr[i] = ex;
        cursor[i] = ex;
    }
}

// XCD-range-partitioned scatter
__global__ void k_scatter(const int* __restrict__ ei, int E, int N,
                          int* __restrict__ cursor, int* __restrict__ col) {
    const int r = blockIdx.x & (NRANGE - 1);
    const int e = (blockIdx.x >> 3) * blockDim.x + threadIdx.x;
    if (e >= E + N) return;
    const int dlo = (int)(((long)r * N) / NRANGE);
    const int dhi = (int)(((long)(r + 1) * N) / NRANGE);
    int d = (e < E) ? ei[E + e] : e - E;
    if (d < dlo || d >= dhi) return;
    int s = (e < E) ? ei[e] : d;
    int pos = atomicAdd(&cursor[d], 1);
    col[pos] = s;
}

// ============================ GEMM1: h1 = x @ W1  (fp32 out + bf16 gather copy) ============================
__global__ void k_gemm1(const float* __restrict__ x, const float* __restrict__ W1,
                        float* __restrict__ h1, bf16* __restrict__ h1b, int N) {
    __shared__ float xs[8][128];
    const int j = threadIdx.x;
    const int row0 = blockIdx.x * 8;
    #pragma unroll
    for (int r = 0; r < 8; ++r) {
        int n = row0 + r;
        xs[r][j] = (n < N) ? x[(long)n * 128 + j] : 0.f;
    }
    __syncthreads();
    float acc[8];
    #pragma unroll
    for (int r = 0; r < 8; ++r) acc[r] = 0.f;
    for (int k = 0; k < 128; ++k) {
        float w = W1[k * 128 + j];
        #pragma unroll
        for (int r = 0; r < 8; ++r) acc[r] = fmaf(xs[r][k], w, acc[r]);
    }
    #pragma unroll
    for (int r = 0; r < 8; ++r) {
        int n = row0 + r;
        if (n < N) {
            h1[(long)n * 128 + j]  = acc[r];
            h1b[(long)n * 128 + j] = __float2bfloat16(acc[r]);
        }
    }
}

// ============================ attention coeffs layer 1 (from fp32 h1) ============================
__global__ void k_att1(const float* __restrict__ h1, const float* __restrict__ as,
                       const float* __restrict__ ad,
                       float* __restrict__ a1s, float* __restrict__ a1d, int N) {
    const int n = blockIdx.x, j = threadIdx.x;   // 128 threads
    float h = h1[(long)n * 128 + j];
    float vs = h * as[j], vd = h * ad[j];
    #pragma unroll
    for (int m = 16; m >= 1; m >>= 1) {
        vs += __shfl_xor(vs, m, 32);
        vd += __shfl_xor(vd, m, 32);
    }
    if ((j & 31) == 0) { a1s[n * 4 + (j >> 5)] = vs; a1d[n * 4 + (j >> 5)] = vd; }
}

// ============================ layer-1 fused softmax+aggregate ============================
__global__ void k_aggr1(const int* __restrict__ rowptr, const int* __restrict__ col,
                        const bf16x2* __restrict__ h1r, const float* __restrict__ a1s,
                        const float* __restrict__ a1d, const float* __restrict__ b1,
                        float* __restrict__ g1, int N) {
    __shared__ float als[4][64][4];
    __shared__ int   scol[4][64];
    const int w = threadIdx.x >> 6;
    const int lane = threadIdx.x & 63;
    const int d = blockIdx.x * 4 + w;
    if (d >= N) return;
    const int lo = rowptr[d], hi = rowptr[d + 1];
    const float4 ad4 = *(const float4*)&a1d[d * 4];

    // ---- phase 1: online softmax stats per head ----
    float mx0 = NEG_BIG, mx1 = NEG_BIG, mx2 = NEG_BIG, mx3 = NEG_BIG;
    float sm0 = 0.f, sm1 = 0.f, sm2 = 0.f, sm3 = 0.f;
    for (int j = lo + lane; j < hi; j += 64) {
        int s = col[j];
        float4 as4 = *(const float4*)&a1s[s * 4];
        float a0 = as4.x + ad4.x, a1 = as4.y + ad4.y, a2 = as4.z + ad4.z, a3 = as4.w + ad4.w;
        a0 = a0 > 0.f ? a0 : NEG_ATT * a0;
        a1 = a1 > 0.f ? a1 : NEG_ATT * a1;
        a2 = a2 > 0.f ? a2 : NEG_ATT * a2;
        a3 = a3 > 0.f ? a3 : NEG_ATT * a3;
        float m;
        m = fmaxf(mx0, a0); sm0 = sm0 * __expf(mx0 - m) + __expf(a0 - m); mx0 = m;
        m = fmaxf(mx1, a1); sm1 = sm1 * __expf(mx1 - m) + __expf(a1 - m); mx1 = m;
        m = fmaxf(mx2, a2); sm2 = sm2 * __expf(mx2 - m) + __expf(a2 - m); mx2 = m;
        m = fmaxf(mx3, a3); sm3 = sm3 * __expf(mx3 - m) + __expf(a3 - m); mx3 = m;
    }
    #pragma unroll
    for (int off = 32; off >= 1; off >>= 1) {
        float mo, so, m;
        mo = __shfl_xor(mx0, off); so = __shfl_xor(sm0, off);
        m = fmaxf(mx0, mo); sm0 = sm0 * __expf(mx0 - m) + so * __expf(mo - m); mx0 = m;
        mo = __shfl_xor(mx1, off); so = __shfl_xor(sm1, off);
        m = fmaxf(mx1, mo); sm1 = sm1 * __expf(mx1 - m) + so * __expf(mo - m); mx1 = m;
        mo = __shfl_xor(mx2, off); so = __shfl_xor(sm2, off);
        m = fmaxf(mx2, mo); sm2 = sm2 * __expf(mx2 - m) + so * __expf(mo - m); mx2 = m;
        mo = __shfl_xor(mx3, off); so = __shfl_xor(sm3, off);
        m = fmaxf(mx3, mo); sm3 = sm3 * __expf(mx3 - m) + so * __expf(mo - m); mx3 = m;
    }
    const float inv0 = 1.f / (sm0 + 1e-16f), inv1 = 1.f / (sm1 + 1e-16f);
    const float inv2 = 1.f / (sm2 + 1e-16f), inv3 = 1.f / (sm3 + 1e-16f);

    // ---- phase 2: chunked alpha precompute + bf16x2 gather ----
    const int hh = lane >> 4;                    // head of channels {2l,2l+1}
    float acc0 = 0.f, acc1 = 0.f;
    for (int base = lo; base < hi; base += 64) {
        const int cnt = min(64, hi - base);
        if (lane < cnt) {
            int s = col[base + lane];
            float4 as4 = *(const float4*)&a1s[s * 4];
            float a0 = as4.x + ad4.x, a1 = as4.y + ad4.y, a2 = as4.z + ad4.z, a3 = as4.w + ad4.w;
            a0 = a0 > 0.f ? a0 : NEG_ATT * a0;
            a1 = a1 > 0.f ? a1 : NEG_ATT * a1;
            a2 = a2 > 0.f ? a2 : NEG_ATT * a2;
            a3 = a3 > 0.f ? a3 : NEG_ATT * a3;
            float4 al;
            al.x = __expf(a0 - mx0) * inv0;
            al.y = __expf(a1 - mx1) * inv1;
            al.z = __expf(a2 - mx2) * inv2;
            al.w = __expf(a3 - mx3) * inv3;
            *(float4*)&als[w][lane][0] = al;
            scol[w][lane] = s;
        }
        __builtin_amdgcn_wave_barrier();
        for (int t = 0; t < cnt; ++t) {
            int s = scol[w][t];
            float al = als[w][t][hh];
            bf16x2 v = h1r[(long)s * 64 + lane];
            acc0 = fmaf(__bfloat162float(v.x), al, acc0);
            acc1 = fmaf(__bfloat162float(v.y), al, acc1);
        }
        __builtin_amdgcn_wave_barrier();
    }
    float2 outv;
    outv.x = acc0 + b1[2 * lane];
    outv.y = acc1 + b1[2 * lane + 1];
    *(float2*)&g1[(long)d * 128 + 2 * lane] = outv;
}

// ============================ GEMM2 fused: h2b = bf16(leaky(g1) @ W2), + a2s/a2d ============================
__global__ void k_gemm2(const float* __restrict__ g1, const float* __restrict__ W2,
                        const float* __restrict__ a2srcv, const float* __restrict__ a2dstv,
                        bf16* __restrict__ h2b, float* __restrict__ a2s, float* __restrict__ a2d,
                        int N) {
    __shared__ float xs[128];
    const int n = blockIdx.x, j = threadIdx.x;   // 64 threads
    for (int t = j; t < 128; t += 64) {
        float v = g1[(long)n * 128 + t];
        xs[t] = v > 0.f ? v : NEG_ACT * v;
    }
    __syncthreads();
    float acc = 0.f;
    for (int k = 0; k < 128; ++k) acc = fmaf(xs[k], W2[k * 64 + j], acc);
    h2b[(long)n * 64 + j] = __float2bfloat16(acc);
    float vs = acc * a2srcv[j], vd = acc * a2dstv[j];
    #pragma unroll
    for (int m = 32; m >= 1; m >>= 1) {
        vs += __shfl_xor(vs, m);
        vd += __shfl_xor(vd, m);
    }
    if (j == 0) { a2s[n] = vs; a2d[n] = vd; }
}

// ============================ layer-2 fused softmax+aggregate ============================
__global__ void k_aggr2(const int* __restrict__ rowptr, const int* __restrict__ col,
                        const bf16x2* __restrict__ h2r, const float* __restrict__ a2s,
                        const float* __restrict__ a2d, const float* __restrict__ b2,
                        float* __restrict__ zout, int N) {
    __shared__ float als[4][64];
    __shared__ int   scol[4][64];
    const int w = threadIdx.x >> 6;
    const int lane = threadIdx.x & 63;
    const int half = lane >> 5, c = lane & 31;
    const int d = blockIdx.x * 4 + w;
    if (d >= N) return;
    const int lo = rowptr[d], hi = rowptr[d + 1];
    const float ad = a2d[d];

    float mx = NEG_BIG, sm = 0.f;
    for (int j = lo + lane; j < hi; j += 64) {
        int s = col[j];
        float a = a2s[s] + ad;
        a = a > 0.f ? a : NEG_ATT * a;
        float m = fmaxf(mx, a);
        sm = sm * __expf(mx - m) + __expf(a - m);
        mx = m;
    }
    #pragma unroll
    for (int off = 32; off >= 1; off >>= 1) {
        float mo = __shfl_xor(mx, off), so = __shfl_xor(sm, off);
        float m = fmaxf(mx, mo);
        sm = sm * __expf(mx - m) + so * __expf(mo - m);
        mx = m;
    }
    const float inv = 1.f / (sm + 1e-16f);

    float acc0 = 0.f, acc1 = 0.f;
    for (int base = lo; base < hi; base += 64) {
        const int cnt = min(64, hi - base);
        if (lane < cnt) {
            int s = col[base + lane];
            float a = a2s[s] + ad;
            a = a > 0.f ? a : NEG_ATT * a;
            als[w][lane] = __expf(a - mx) * inv;
            scol[w][lane] = s;
        }
        __builtin_amdgcn_wave_barrier();
        for (int t = 0; t < cnt; t += 2) {
            int tt = t + half;
            if (tt < cnt) {
                int s = scol[w][tt];
                float al = als[w][tt];
                bf16x2 v = h2r[(long)s * 32 + c];
                acc0 = fmaf(__bfloat162float(v.x), al, acc0);
                acc1 = fmaf(__bfloat162float(v.y), al, acc1);
            }
        }
        __builtin_amdgcn_wave_barrier();
    }
    acc0 += __shfl_xor(acc0, 32);
    acc1 += __shfl_xor(acc1, 32);
    if (half == 0) {
        float2 outv;
        outv.x = acc0 + b2[2 * c];
        outv.y = acc1 + b2[2 * c + 1];
        *(float2*)&zout[(long)d * 64 + 2 * c] = outv;
    }
}

// ============================ decoder node-level precompute (bf16 out) ============================
__global__ void k_uv(const float* __restrict__ z, const float* __restrict__ Wd1,
                     const float* __restrict__ bd1,
                     bf16* __restrict__ u, bf16* __restrict__ v, int N) {
    __shared__ float zs[4][64];
    const int w = threadIdx.x >> 6;              // node slot 0..3
    const int lane = threadIdx.x & 63;
    const int n = blockIdx.x * 4 + w;
    if (n < N) zs[w][lane] = z[(long)n * 64 + lane];
    __syncthreads();
    if (n >= N) return;
    const int jj = lane & 31;
    const int base = (lane < 32) ? 0 : 64 * 32;  // top half -> u, bottom -> v
    float acc = (lane < 32) ? bd1[jj] : 0.f;
    #pragma unroll
    for (int k = 0; k < 64; ++k)
        acc = fmaf(zs[w][k], Wd1[base + k * 32 + jj], acc);
    if (lane < 32) u[(long)n * 32 + jj] = __float2bfloat16(acc);
    else           v[(long)n * 32 + jj] = __float2bfloat16(acc);
}

// ============================ decoder per-edge: relu(u[s]+v[d]) . Wd2 + bd2 ============================
__global__ void k_dec2(const int* __restrict__ ei, int E,
                       const bf16* __restrict__ u, const bf16* __restrict__ v,
                       const float* __restrict__ Wd2, const float* __restrict__ bd2,
                       float* __restrict__ pred) {
    const int g = threadIdx.x >> 3;      // edge slot 0..31
    const int l = threadIdx.x & 7;       // lane in group
    long e = (long)blockIdx.x * 32 + g;
    if (e >= E) return;
    int s = ei[e], d = ei[E + e];
    uint2 ua = *(const uint2*)(u + (long)s * 32 + l * 4);
    uint2 vb = *(const uint2*)(v + (long)d * 32 + l * 4);
    bf16x2 ua0 = *(bf16x2*)&ua.x, ua1 = *(bf16x2*)&ua.y;
    bf16x2 vb0 = *(bf16x2*)&vb.x, vb1 = *(bf16x2*)&vb.y;
    float4 wv = *(const float4*)&Wd2[l * 4];
    float h0 = fmaxf(__bfloat162float(ua0.x) + __bfloat162float(vb0.x), 0.f);
    float h1 = fmaxf(__bfloat162float(ua0.y) + __bfloat162float(vb0.y), 0.f);
    float h2 = fmaxf(__bfloat162float(ua1.x) + __bfloat162float(vb1.x), 0.f);
    float h3 = fmaxf(__bfloat162float(ua1.y) + __bfloat162float(vb1.y), 0.f);
    float p = h0 * wv.x;
    p = fmaf(h1, wv.y, p);
    p = fmaf(h2, wv.z, p);
    p = fmaf(h3, wv.w, p);
    p += __shfl_xor(p, 1, 8);
    p += __shfl_xor(p, 2, 8);
    p += __shfl_xor(p, 4, 8);
    if (l == 0) pred[e] = p + bd2[0];
}

// ============================ launch ============================
extern "C" void kernel_launch(void* const* d_in, const int* in_sizes, int n_in,
                              void* d_out, int out_size, void* d_ws, size_t ws_size,
                              hipStream_t stream) {
    const float* x    = (const float*)d_in[0];
    const int*   ei   = (const int*)d_in[1];
    const float* W1   = (const float*)d_in[2];
    const float* a1sw = (const float*)d_in[3];
    const float* a1dw = (const float*)d_in[4];
    const float* b1   = (const float*)d_in[5];
    const float* W2   = (const float*)d_in[6];
    const float* a2sw = (const float*)d_in[7];
    const float* a2dw = (const float*)d_in[8];
    const float* b2   = (const float*)d_in[9];
    const float* Wd1  = (const float*)d_in[10];
    const float* bd1  = (const float*)d_in[11];
    const float* Wd2  = (const float*)d_in[12];
    const float* bd2  = (const float*)d_in[13];

    const int N = in_sizes[0] / 128;        // 50000
    const int E = in_sizes[1] / 2;          // 1600000
    const int E2 = E + N;

    float* pred = (float*)d_out;            // [E]
    float* zout = (float*)d_out + E;        // [N,64]

    // workspace layout (float-slot units)
    float* W = (float*)d_ws;
    size_t o = 0;
    float* h1  = W + o; o += (size_t)N * 128;
    float* g1  = W + o; o += (size_t)N * 128;
    bf16* h1b  = (bf16*)(W + o); o += (size_t)N * 64;   // N*128 bf16
    bf16* h2b  = (bf16*)(W + o); o += (size_t)N * 32;   // N*64 bf16
    bf16* ub   = (bf16*)(W + o); o += (size_t)N * 16;   // N*32 bf16
    bf16* vb   = (bf16*)(W + o); o += (size_t)N * 16;   // N*32 bf16
    float* a1s = W + o; o += (size_t)N * 4;
    float* a1d = W + o; o += (size_t)N * 4;
    float* a2s = W + o; o += (size_t)N;
    float* a2d = W + o; o += (size_t)N;
    int* counts = (int*)(W + o); o += (size_t)N;
    int* rowptr = (int*)(W + o); o += (size_t)N + 1;
    int* cursor = (int*)(W + o); o += (size_t)N;
    int* col    = (int*)(W + o); o += (size_t)E2;
    int* bsum   = (int*)(W + o); o += 256;
    if (ws_size < o * sizeof(float)) return;

    const int TB = 256;
    const int gE = (E2 + TB - 1) / TB;
    const int NB = (N + 255) / 256;         // 196 scan blocks

    // CSR build
    k_zero<<<(N + TB - 1) / TB, TB, 0, stream>>>(counts, N);
    k_count<<<gE * NRANGE, TB, 0, stream>>>(ei, E, N, counts);
    k_scan1<<<NB, 256, 0, stream>>>(counts, N, bsum);
    k_scan2<<<1, 256, 0, stream>>>(bsum, NB, &rowptr[N]);
    k_scan3<<<NB, 256, 0, stream>>>(counts, N, bsum, rowptr, cursor);
    k_scatter<<<gE * NRANGE, TB, 0, stream>>>(ei, E, N, cursor, col);

    // layer 1
    k_gemm1<<<(N + 7) / 8, 128, 0, stream>>>(x, W1, h1, h1b, N);
    k_att1<<<N, 128, 0, stream>>>(h1, a1sw, a1dw, a1s, a1d, N);
    k_aggr1<<<(N + 3) / 4, 256, 0, stream>>>(rowptr, col, (const bf16x2*)h1b, a1s, a1d, b1, g1, N);

    // layer 2
    k_gemm2<<<N, 64, 0, stream>>>(g1, W2, a2sw, a2dw, h2b, a2s, a2d, N);
    k_aggr2<<<(N + 3) / 4, 256, 0, stream>>>(rowptr, col, (const bf16x2*)h2b, a2s, a2d, b2, zout, N);

    // decoder (split: first layer is linear over the concat)
    k_uv<<<(N + 3) / 4, 256, 0, stream>>>(zout, Wd1, bd1, ub, vb, N);
    k_dec2<<<(E + 31) / 32, TB, 0, stream>>>(ei, E, ub, vb, Wd2, bd2, pred);
}

// Round 8
// 450.776 us; speedup vs baseline: 12.9811x; 1.0135x over previous
//
#include <hip/hip_runtime.h>
#include <hip/hip_bf16.h>
#include <math.h>

#define NEG_ATT 0.2f
#define NEG_ACT 0.01f
#define NEG_BIG -1e30f
#define NRANGE 8   // dst-space ranges, mapped to XCDs via blockIdx%8

typedef __hip_bfloat16  bf16;
typedef __hip_bfloat162 bf16x2;

__device__ __forceinline__ float bflo(unsigned w) { return __uint_as_float(w << 16); }
__device__ __forceinline__ float bfhi(unsigned w) { return __uint_as_float(w & 0xFFFF0000u); }

// ============================ CSR build ============================
__global__ void k_zero(int* __restrict__ counts, int N) {
    int i = blockIdx.x * blockDim.x + threadIdx.x;
    if (i < N) counts[i] = 0;
}

__global__ void k_count(const int* __restrict__ ei, int E, int N, int* __restrict__ counts) {
    const int r = blockIdx.x & (NRANGE - 1);
    const int e = (blockIdx.x >> 3) * blockDim.x + threadIdx.x;
    if (e >= E + N) return;
    const int dlo = (int)(((long)r * N) / NRANGE);
    const int dhi = (int)(((long)(r + 1) * N) / NRANGE);
    int d = (e < E) ? ei[E + e] : e - E;
    if (d < dlo || d >= dhi) return;
    atomicAdd(&counts[d], 1);
}

__global__ void k_scan1(const int* __restrict__ counts, int N, int* __restrict__ bsum) {
    const int i = blockIdx.x * 256 + threadIdx.x;
    int v = (i < N) ? counts[i] : 0;
    #pragma unroll
    for (int off = 32; off >= 1; off >>= 1) v += __shfl_xor(v, off);
    __shared__ int ws[4];
    if ((threadIdx.x & 63) == 0) ws[threadIdx.x >> 6] = v;
    __syncthreads();
    if (threadIdx.x == 0) bsum[blockIdx.x] = ws[0] + ws[1] + ws[2] + ws[3];
}

__global__ void k_scan2(int* __restrict__ bsum, int NB, int* __restrict__ rowptrN) {
    __shared__ int ps[256];
    const int t = threadIdx.x;
    int v = (t < NB) ? bsum[t] : 0;
    ps[t] = v;
    __syncthreads();
    for (int off = 1; off < 256; off <<= 1) {
        int u = (t >= off) ? ps[t - off] : 0;
        __syncthreads();
        ps[t] += u;
        __syncthreads();
    }
    if (t < NB) bsum[t] = ps[t] - v;          // exclusive
    if (t == 255) *rowptrN = ps[255];         // total
}

__global__ void k_scan3(const int* __restrict__ counts, int N, const int* __restrict__ bsum,
                        int* __restrict__ rowptr, int* __restrict__ cursor) {
    __shared__ int ps[256];
    const int t = threadIdx.x;
    const int i = blockIdx.x * 256 + t;
    int v = (i < N) ? counts[i] : 0;
    ps[t] = v;
    __syncthreads();
    for (int off = 1; off < 256; off <<= 1) {
        int u = (t >= off) ? ps[t - off] : 0;
        __syncthreads();
        ps[t] += u;
        __syncthreads();
    }
    if (i < N) {
        int ex = ps[t] - v + bsum[blockIdx.x];
        rowptr[i] = ex;
        cursor[i] = ex;
    }
}

__global__ void k_scatter(const int* __restrict__ ei, int E, int N,
                          int* __restrict__ cursor, int* __restrict__ col) {
    const int r = blockIdx.x & (NRANGE - 1);
    const int e = (blockIdx.x >> 3) * blockDim.x + threadIdx.x;
    if (e >= E + N) return;
    const int dlo = (int)(((long)r * N) / NRANGE);
    const int dhi = (int)(((long)(r + 1) * N) / NRANGE);
    int d = (e < E) ? ei[E + e] : e - E;
    if (d < dlo || d >= dhi) return;
    int s = (e < E) ? ei[e] : d;
    int pos = atomicAdd(&cursor[d], 1);
    col[pos] = s;
}

// ============================ GEMM1 fused with att1: h1b = bf16(x@W1), a1s/a1d ============================
__global__ void k_gemm1(const float* __restrict__ x, const float* __restrict__ W1,
                        const float* __restrict__ a1sw, const float* __restrict__ a1dw,
                        bf16* __restrict__ h1b, float* __restrict__ a1s, float* __restrict__ a1d,
                        int N) {
    __shared__ float xs[8][128];
    const int j = threadIdx.x;
    const int row0 = blockIdx.x * 8;
    #pragma unroll
    for (int r = 0; r < 8; ++r) {
        int n = row0 + r;
        xs[r][j] = (n < N) ? x[(long)n * 128 + j] : 0.f;
    }
    __syncthreads();
    float acc[8];
    #pragma unroll
    for (int r = 0; r < 8; ++r) acc[r] = 0.f;
    for (int k = 0; k < 128; ++k) {
        float w = W1[k * 128 + j];
        #pragma unroll
        for (int r = 0; r < 8; ++r) acc[r] = fmaf(xs[r][k], w, acc[r]);
    }
    const float asw = a1sw[j], adw = a1dw[j];
    #pragma unroll
    for (int r = 0; r < 8; ++r) {
        int n = row0 + r;
        float vs = acc[r] * asw, vd = acc[r] * adw;
        #pragma unroll
        for (int m = 16; m >= 1; m >>= 1) {
            vs += __shfl_xor(vs, m, 32);
            vd += __shfl_xor(vd, m, 32);
        }
        if (n < N) {
            h1b[(long)n * 128 + j] = __float2bfloat16(acc[r]);
            if ((j & 31) == 0) { a1s[n * 4 + (j >> 5)] = vs; a1d[n * 4 + (j >> 5)] = vd; }
        }
    }
}

// ============================ layer-1 fused softmax+aggregate ============================
// phase 2: half-wave per edge (2 edges/iter); lane owns 4 channels {4c..4c+3} via one uint2 (bf16x4) load.
__global__ void k_aggr1(const int* __restrict__ rowptr, const int* __restrict__ col,
                        const uint2* __restrict__ h1q, const float* __restrict__ a1s,
                        const float* __restrict__ a1d, const float* __restrict__ b1,
                        float* __restrict__ g1, int N) {
    __shared__ float als[4][64][4];
    __shared__ int   scol[4][64];
    const int w = threadIdx.x >> 6;
    const int lane = threadIdx.x & 63;
    const int d = blockIdx.x * 4 + w;
    if (d >= N) return;
    const int lo = rowptr[d], hi = rowptr[d + 1];
    const float4 ad4 = *(const float4*)&a1d[d * 4];

    // ---- phase 1: online softmax stats per head ----
    float mx0 = NEG_BIG, mx1 = NEG_BIG, mx2 = NEG_BIG, mx3 = NEG_BIG;
    float sm0 = 0.f, sm1 = 0.f, sm2 = 0.f, sm3 = 0.f;
    for (int j = lo + lane; j < hi; j += 64) {
        int s = col[j];
        float4 as4 = *(const float4*)&a1s[s * 4];
        float a0 = as4.x + ad4.x, a1 = as4.y + ad4.y, a2 = as4.z + ad4.z, a3 = as4.w + ad4.w;
        a0 = a0 > 0.f ? a0 : NEG_ATT * a0;
        a1 = a1 > 0.f ? a1 : NEG_ATT * a1;
        a2 = a2 > 0.f ? a2 : NEG_ATT * a2;
        a3 = a3 > 0.f ? a3 : NEG_ATT * a3;
        float m;
        m = fmaxf(mx0, a0); sm0 = sm0 * __expf(mx0 - m) + __expf(a0 - m); mx0 = m;
        m = fmaxf(mx1, a1); sm1 = sm1 * __expf(mx1 - m) + __expf(a1 - m); mx1 = m;
        m = fmaxf(mx2, a2); sm2 = sm2 * __expf(mx2 - m) + __expf(a2 - m); mx2 = m;
        m = fmaxf(mx3, a3); sm3 = sm3 * __expf(mx3 - m) + __expf(a3 - m); mx3 = m;
    }
    #pragma unroll
    for (int off = 32; off >= 1; off >>= 1) {
        float mo, so, m;
        mo = __shfl_xor(mx0, off); so = __shfl_xor(sm0, off);
        m = fmaxf(mx0, mo); sm0 = sm0 * __expf(mx0 - m) + so * __expf(mo - m); mx0 = m;
        mo = __shfl_xor(mx1, off); so = __shfl_xor(sm1, off);
        m = fmaxf(mx1, mo); sm1 = sm1 * __expf(mx1 - m) + so * __expf(mo - m); mx1 = m;
        mo = __shfl_xor(mx2, off); so = __shfl_xor(sm2, off);
        m = fmaxf(mx2, mo); sm2 = sm2 * __expf(mx2 - m) + so * __expf(mo - m); mx2 = m;
        mo = __shfl_xor(mx3, off); so = __shfl_xor(sm3, off);
        m = fmaxf(mx3, mo); sm3 = sm3 * __expf(mx3 - m) + so * __expf(mo - m); mx3 = m;
    }
    const float inv0 = 1.f / (sm0 + 1e-16f), inv1 = 1.f / (sm1 + 1e-16f);
    const float inv2 = 1.f / (sm2 + 1e-16f), inv3 = 1.f / (sm3 + 1e-16f);

    // ---- phase 2 ----
    const int half = lane >> 5;          // which edge of the pair
    const int c = lane & 31;             // 4-channel group: channels 4c..4c+3
    const int hh = c >> 3;               // head of this group
    float ac0 = 0.f, ac1 = 0.f, ac2 = 0.f, ac3 = 0.f;
    for (int base = lo; base < hi; base += 64) {
        const int cnt = min(64, hi - base);
        if (lane < cnt) {
            int s = col[base + lane];
            float4 as4 = *(const float4*)&a1s[s * 4];
            float a0 = as4.x + ad4.x, a1 = as4.y + ad4.y, a2 = as4.z + ad4.z, a3 = as4.w + ad4.w;
            a0 = a0 > 0.f ? a0 : NEG_ATT * a0;
            a1 = a1 > 0.f ? a1 : NEG_ATT * a1;
            a2 = a2 > 0.f ? a2 : NEG_ATT * a2;
            a3 = a3 > 0.f ? a3 : NEG_ATT * a3;
            float4 al;
            al.x = __expf(a0 - mx0) * inv0;
            al.y = __expf(a1 - mx1) * inv1;
            al.z = __expf(a2 - mx2) * inv2;
            al.w = __expf(a3 - mx3) * inv3;
            *(float4*)&als[w][lane][0] = al;
            scol[w][lane] = s;
        }
        __builtin_amdgcn_wave_barrier();
        for (int t = 0; t < cnt; t += 2) {
            int tt = t + half;
            if (tt < cnt) {
                unsigned s = (unsigned)scol[w][tt];
                float al = als[w][tt][hh];
                uint2 v = h1q[s * 32u + (unsigned)c];
                ac0 = fmaf(bflo(v.x), al, ac0);
                ac1 = fmaf(bfhi(v.x), al, ac1);
                ac2 = fmaf(bflo(v.y), al, ac2);
                ac3 = fmaf(bfhi(v.y), al, ac3);
            }
        }
        __builtin_amdgcn_wave_barrier();
    }
    ac0 += __shfl_xor(ac0, 32);
    ac1 += __shfl_xor(ac1, 32);
    ac2 += __shfl_xor(ac2, 32);
    ac3 += __shfl_xor(ac3, 32);
    if (half == 0) {
        float4 bv = *(const float4*)&b1[4 * c];
        float4 outv;
        outv.x = ac0 + bv.x; outv.y = ac1 + bv.y;
        outv.z = ac2 + bv.z; outv.w = ac3 + bv.w;
        *(float4*)&g1[(long)d * 128 + 4 * c] = outv;
    }
}

// ============================ GEMM2 fused: h2b = bf16(leaky(g1) @ W2), + a2s/a2d ============================
__global__ void k_gemm2(const float* __restrict__ g1, const float* __restrict__ W2,
                        const float* __restrict__ a2srcv, const float* __restrict__ a2dstv,
                        bf16* __restrict__ h2b, float* __restrict__ a2s, float* __restrict__ a2d,
                        int N) {
    __shared__ float xs[128];
    const int n = blockIdx.x, j = threadIdx.x;   // 64 threads
    for (int t = j; t < 128; t += 64) {
        float v = g1[(long)n * 128 + t];
        xs[t] = v > 0.f ? v : NEG_ACT * v;
    }
    __syncthreads();
    float acc = 0.f;
    for (int k = 0; k < 128; ++k) acc = fmaf(xs[k], W2[k * 64 + j], acc);
    h2b[(long)n * 64 + j] = __float2bfloat16(acc);
    float vs = acc * a2srcv[j], vd = acc * a2dstv[j];
    #pragma unroll
    for (int m = 32; m >= 1; m >>= 1) {
        vs += __shfl_xor(vs, m);
        vd += __shfl_xor(vd, m);
    }
    if (j == 0) { a2s[n] = vs; a2d[n] = vd; }
}

// ============================ layer-2 fused softmax+aggregate ============================
// phase 2: 16 lanes per edge (4 edges/iter); lane owns channels {4c..4c+3} via one uint2 load.
__global__ void k_aggr2(const int* __restrict__ rowptr, const int* __restrict__ col,
                        const uint2* __restrict__ h2q, const float* __restrict__ a2s,
                        const float* __restrict__ a2d, const float* __restrict__ b2,
                        float* __restrict__ zout, int N) {
    __shared__ float als[4][64];
    __shared__ int   scol[4][64];
    const int w = threadIdx.x >> 6;
    const int lane = threadIdx.x & 63;
    const int q = lane >> 4;             // edge slot in quad
    const int c = lane & 15;             // 4-channel group: channels 4c..4c+3
    const int d = blockIdx.x * 4 + w;
    if (d >= N) return;
    const int lo = rowptr[d], hi = rowptr[d + 1];
    const float ad = a2d[d];

    float mx = NEG_BIG, sm = 0.f;
    for (int j = lo + lane; j < hi; j += 64) {
        int s = col[j];
        float a = a2s[s] + ad;
        a = a > 0.f ? a : NEG_ATT * a;
        float m = fmaxf(mx, a);
        sm = sm * __expf(mx - m) + __expf(a - m);
        mx = m;
    }
    #pragma unroll
    for (int off = 32; off >= 1; off >>= 1) {
        float mo = __shfl_xor(mx, off), so = __shfl_xor(sm, off);
        float m = fmaxf(mx, mo);
        sm = sm * __expf(mx - m) + so * __expf(mo - m);
        mx = m;
    }
    const float inv = 1.f / (sm + 1e-16f);

    float ac0 = 0.f, ac1 = 0.f, ac2 = 0.f, ac3 = 0.f;
    for (int base = lo; base < hi; base += 64) {
        const int cnt = min(64, hi - base);
        if (lane < cnt) {
            int s = col[base + lane];
            float a = a2s[s] + ad;
            a = a > 0.f ? a : NEG_ATT * a;
            als[w][lane] = __expf(a - mx) * inv;
            scol[w][lane] = s;
        }
        __builtin_amdgcn_wave_barrier();
        for (int t = 0; t < cnt; t += 4) {
            int tt = t + q;
            if (tt < cnt) {
                unsigned s = (unsigned)scol[w][tt];
                float al = als[w][tt];
                uint2 v = h2q[s * 16u + (unsigned)c];
                ac0 = fmaf(bflo(v.x), al, ac0);
                ac1 = fmaf(bfhi(v.x), al, ac1);
                ac2 = fmaf(bflo(v.y), al, ac2);
                ac3 = fmaf(bfhi(v.y), al, ac3);
            }
        }
        __builtin_amdgcn_wave_barrier();
    }
    #pragma unroll
    for (int off = 16; off <= 32; off <<= 1) {
        ac0 += __shfl_xor(ac0, off);
        ac1 += __shfl_xor(ac1, off);
        ac2 += __shfl_xor(ac2, off);
        ac3 += __shfl_xor(ac3, off);
    }
    if (lane < 16) {
        float4 bv = *(const float4*)&b2[4 * c];
        float4 outv;
        outv.x = ac0 + bv.x; outv.y = ac1 + bv.y;
        outv.z = ac2 + bv.z; outv.w = ac3 + bv.w;
        *(float4*)&zout[(long)d * 64 + 4 * c] = outv;
    }
}

// ============================ decoder node-level precompute (bf16 out) ============================
__global__ void k_uv(const float* __restrict__ z, const float* __restrict__ Wd1,
                     const float* __restrict__ bd1,
                     bf16* __restrict__ u, bf16* __restrict__ v, int N) {
    __shared__ float zs[4][64];
    const int w = threadIdx.x >> 6;              // node slot 0..3
    const int lane = threadIdx.x & 63;
    const int n = blockIdx.x * 4 + w;
    if (n < N) zs[w][lane] = z[(long)n * 64 + lane];
    __syncthreads();
    if (n >= N) return;
    const int jj = lane & 31;
    const int base = (lane < 32) ? 0 : 64 * 32;  // top half -> u, bottom -> v
    float acc = (lane < 32) ? bd1[jj] : 0.f;
    #pragma unroll
    for (int k = 0; k < 64; ++k)
        acc = fmaf(zs[w][k], Wd1[base + k * 32 + jj], acc);
    if (lane < 32) u[(long)n * 32 + jj] = __float2bfloat16(acc);
    else           v[(long)n * 32 + jj] = __float2bfloat16(acc);
}

// ============================ decoder per-edge: relu(u[s]+v[d]) . Wd2 + bd2 ============================
__global__ void k_dec2(const int* __restrict__ ei, int E,
                       const bf16* __restrict__ u, const bf16* __restrict__ v,
                       const float* __restrict__ Wd2, const float* __restrict__ bd2,
                       float* __restrict__ pred) {
    const int g = threadIdx.x >> 3;      // edge slot 0..31
    const int l = threadIdx.x & 7;       // lane in group
    long e = (long)blockIdx.x * 32 + g;
    if (e >= E) return;
    int s = ei[e], d = ei[E + e];
    uint2 ua = *(const uint2*)(u + (long)s * 32 + l * 4);
    uint2 vb = *(const uint2*)(v + (long)d * 32 + l * 4);
    float4 wv = *(const float4*)&Wd2[l * 4];
    float h0 = fmaxf(bflo(ua.x) + bflo(vb.x), 0.f);
    float h1 = fmaxf(bfhi(ua.x) + bfhi(vb.x), 0.f);
    float h2 = fmaxf(bflo(ua.y) + bflo(vb.y), 0.f);
    float h3 = fmaxf(bfhi(ua.y) + bfhi(vb.y), 0.f);
    float p = h0 * wv.x;
    p = fmaf(h1, wv.y, p);
    p = fmaf(h2, wv.z, p);
    p = fmaf(h3, wv.w, p);
    p += __shfl_xor(p, 1, 8);
    p += __shfl_xor(p, 2, 8);
    p += __shfl_xor(p, 4, 8);
    if (l == 0) pred[e] = p + bd2[0];
}

// ============================ launch ============================
extern "C" void kernel_launch(void* const* d_in, const int* in_sizes, int n_in,
                              void* d_out, int out_size, void* d_ws, size_t ws_size,
                              hipStream_t stream) {
    const float* x    = (const float*)d_in[0];
    const int*   ei   = (const int*)d_in[1];
    const float* W1   = (const float*)d_in[2];
    const float* a1sw = (const float*)d_in[3];
    const float* a1dw = (const float*)d_in[4];
    const float* b1   = (const float*)d_in[5];
    const float* W2   = (const float*)d_in[6];
    const float* a2sw = (const float*)d_in[7];
    const float* a2dw = (const float*)d_in[8];
    const float* b2   = (const float*)d_in[9];
    const float* Wd1  = (const float*)d_in[10];
    const float* bd1  = (const float*)d_in[11];
    const float* Wd2  = (const float*)d_in[12];
    const float* bd2  = (const float*)d_in[13];

    const int N = in_sizes[0] / 128;        // 50000
    const int E = in_sizes[1] / 2;          // 1600000
    const int E2 = E + N;

    float* pred = (float*)d_out;            // [E]
    float* zout = (float*)d_out + E;        // [N,64]

    // workspace layout (float-slot units)
    float* W = (float*)d_ws;
    size_t o = 0;
    float* g1  = W + o; o += (size_t)N * 128;
    bf16* h1b  = (bf16*)(W + o); o += (size_t)N * 64;   // N*128 bf16
    bf16* h2b  = (bf16*)(W + o); o += (size_t)N * 32;   // N*64 bf16
    bf16* ub   = (bf16*)(W + o); o += (size_t)N * 16;   // N*32 bf16
    bf16* vb   = (bf16*)(W + o); o += (size_t)N * 16;   // N*32 bf16
    float* a1s = W + o; o += (size_t)N * 4;
    float* a1d = W + o; o += (size_t)N * 4;
    float* a2s = W + o; o += (size_t)N;
    float* a2d = W + o; o += (size_t)N;
    int* counts = (int*)(W + o); o += (size_t)N;
    int* rowptr = (int*)(W + o); o += (size_t)N + 1;
    int* cursor = (int*)(W + o); o += (size_t)N;
    int* col    = (int*)(W + o); o += (size_t)E2;
    int* bsum   = (int*)(W + o); o += 256;
    if (ws_size < o * sizeof(float)) return;

    const int TB = 256;
    const int gE = (E2 + TB - 1) / TB;
    const int NB = (N + 255) / 256;

    // CSR build
    k_zero<<<(N + TB - 1) / TB, TB, 0, stream>>>(counts, N);
    k_count<<<gE * NRANGE, TB, 0, stream>>>(ei, E, N, counts);
    k_scan1<<<NB, 256, 0, stream>>>(counts, N, bsum);
    k_scan2<<<1, 256, 0, stream>>>(bsum, NB, &rowptr[N]);
    k_scan3<<<NB, 256, 0, stream>>>(counts, N, bsum, rowptr, cursor);
    k_scatter<<<gE * NRANGE, TB, 0, stream>>>(ei, E, N, cursor, col);

    // layer 1 (att1 fused into gemm1)
    k_gemm1<<<(N + 7) / 8, 128, 0, stream>>>(x, W1, a1sw, a1dw, h1b, a1s, a1d, N);
    k_aggr1<<<(N + 3) / 4, 256, 0, stream>>>(rowptr, col, (const uint2*)h1b, a1s, a1d, b1, g1, N);

    // layer 2
    k_gemm2<<<N, 64, 0, stream>>>(g1, W2, a2sw, a2dw, h2b, a2s, a2d, N);
    k_aggr2<<<(N + 3) / 4, 256, 0, stream>>>(rowptr, col, (const uint2*)h2b, a2s, a2d, b2, zout, N);

    // decoder
    k_uv<<<(N + 3) / 4, 256, 0, stream>>>(zout, Wd1, bd1, ub, vb, N);
    k_dec2<<<(E + 31) / 32, TB, 0, stream>>>(ei, E, ub, vb, Wd2, bd2, pred);
}